// Round 8
// baseline (255.153 us; speedup 1.0000x reference)
//
#include <hip/hip_runtime.h>
#include <hip/hip_bf16.h>
#include <math.h>

#define NT 2048
#define EMBD 512
#define NH 8
#define QKV_LD 1536
#define KSPLIT 8

typedef unsigned short u16;
typedef __attribute__((ext_vector_type(8))) short short8;
typedef __attribute__((ext_vector_type(4))) float v4f;

static __device__ __forceinline__ float bf2f(unsigned int u) {
    union { unsigned int i; float f; } c; c.i = u << 16; return c.f;
}
static __device__ __forceinline__ unsigned int f2bf(float x) {   // RNE
    union { float f; unsigned int u; } c; c.f = x;
    return (c.u + 0x7fffu + ((c.u >> 16) & 1u)) >> 16;
}
// HW packed f32->bf16 (RNE, bit-identical to f2bf pair) — one inst per pair
static __device__ __forceinline__ unsigned int cvtpk(float lo, float hi) {
    unsigned int r;
    asm("v_cvt_pk_bf16_f32 %0, %1, %2" : "=v"(r) : "v"(lo), "v"(hi));
    return r;
}

// ------- prep: split x (hi/lo) + split+transpose Wqkv and Wout --------------
__global__ __launch_bounds__(256) void prep(const float* __restrict__ x,
    u16* __restrict__ xh, u16* __restrict__ xl,
    const float* __restrict__ Wqkv, u16* __restrict__ wth, u16* __restrict__ wtl,
    const float* __restrict__ Wout, u16* __restrict__ woth, u16* __restrict__ wotl)
{
    __shared__ float tile[64][65];
    int b = blockIdx.x;
    const int t = threadIdx.x;
    if (b < 1024) {                       // ---- split_x region
        int i = (b * 256 + t) << 2;
        float4 v = *(const float4*)(x + i);
        float f[4] = {v.x, v.y, v.z, v.w};
        unsigned int hi[4], lo[4];
#pragma unroll
        for (int j = 0; j < 4; ++j) {
            hi[j] = f2bf(f[j]);
            lo[j] = f2bf(f[j] - bf2f(hi[j]));
        }
        uint2 wh; wh.x = hi[0] | (hi[1] << 16); wh.y = hi[2] | (hi[3] << 16);
        uint2 wl; wl.x = lo[0] | (lo[1] << 16); wl.y = lo[2] | (lo[3] << 16);
        *(uint2*)(xh + i) = wh;
        *(uint2*)(xl + i) = wl;
        return;
    }
    b -= 1024;                            // ---- split_wt regions
    const float* W; u16* th; u16* tl; int ld, bx, by;
    if (b < 192) { W = Wqkv; th = wth;  tl = wtl;  ld = QKV_LD; bx = b % 24; by = b / 24; }
    else { b -= 192; W = Wout; th = woth; tl = wotl; ld = EMBD; bx = b & 7; by = b >> 3; }
    const int n0 = bx << 6, k0 = by << 6;
    const int r = t >> 2, c4 = (t & 3) << 4;
#pragma unroll
    for (int j = 0; j < 4; ++j)
        *(float4*)&tile[r][c4 + (j << 2)] =
            *(const float4*)(W + (size_t)(k0 + r) * ld + n0 + c4 + (j << 2));
    __syncthreads();
    const int n_l = t >> 2;
    u16 vh[16], vl[16];
#pragma unroll
    for (int j = 0; j < 16; ++j) {
        float f = tile[c4 + j][n_l];
        unsigned int h = f2bf(f);
        vh[j] = (u16)h;
        vl[j] = (u16)f2bf(f - bf2f(h));
    }
    u16* dh = th + (size_t)(n0 + n_l) * EMBD + k0 + c4;
    u16* dl = tl + (size_t)(n0 + n_l) * EMBD + k0 + c4;
    *(uint4*)dh       = *(uint4*)&vh[0];
    *(uint4*)(dh + 8) = *(uint4*)&vh[8];
    *(uint4*)dl       = *(uint4*)&vl[0];
    *(uint4*)(dl + 8) = *(uint4*)&vl[8];
}

// ------- qkv = x @ Wqkv + b via split-precision bf16 MFMA -------------------
__global__ __launch_bounds__(256) void gemm_qkv_mfma(const u16* __restrict__ xh,
    const u16* __restrict__ xl, const u16* __restrict__ wth,
    const u16* __restrict__ wtl, const float* __restrict__ bias,
    u16* __restrict__ qkvb)
{
    const int n0 = blockIdx.x << 6, m0 = blockIdx.y << 6;
    const int w = threadIdx.x >> 6, lane = threadIdx.x & 63;
    const int wm = w >> 1, wn = w & 1;
    const int fr = lane & 15, kd = (lane >> 4) << 3;

    const u16* ah0 = xh + (size_t)(m0 + wm * 32 + fr) * EMBD + kd;
    const u16* al0 = xl + (size_t)(m0 + wm * 32 + fr) * EMBD + kd;
    const u16* bh0 = wth + (size_t)(n0 + wn * 32 + fr) * EMBD + kd;
    const u16* bl0 = wtl + (size_t)(n0 + wn * 32 + fr) * EMBD + kd;

    v4f acc[2][2] = {};
    for (int kc = 0; kc < EMBD; kc += 32) {
        short8 a_h[2], a_l[2], b_h[2], b_l[2];
#pragma unroll
        for (int im = 0; im < 2; ++im) {
            a_h[im] = *(const short8*)(ah0 + (size_t)im * 16 * EMBD + kc);
            a_l[im] = *(const short8*)(al0 + (size_t)im * 16 * EMBD + kc);
        }
#pragma unroll
        for (int in = 0; in < 2; ++in) {
            b_h[in] = *(const short8*)(bh0 + (size_t)in * 16 * EMBD + kc);
            b_l[in] = *(const short8*)(bl0 + (size_t)in * 16 * EMBD + kc);
        }
#pragma unroll
        for (int im = 0; im < 2; ++im)
#pragma unroll
            for (int in = 0; in < 2; ++in) {
                acc[im][in] = __builtin_amdgcn_mfma_f32_16x16x32_bf16(a_h[im], b_h[in], acc[im][in], 0, 0, 0);
                acc[im][in] = __builtin_amdgcn_mfma_f32_16x16x32_bf16(a_h[im], b_l[in], acc[im][in], 0, 0, 0);
                acc[im][in] = __builtin_amdgcn_mfma_f32_16x16x32_bf16(a_l[im], b_h[in], acc[im][in], 0, 0, 0);
            }
    }
    const int qr = (lane >> 4) << 2;
#pragma unroll
    for (int im = 0; im < 2; ++im)
#pragma unroll
        for (int in = 0; in < 2; ++in) {
            int n = n0 + wn * 32 + in * 16 + fr;
            float bv = bias[n];
#pragma unroll
            for (int r = 0; r < 4; ++r) {
                int m = m0 + wm * 32 + im * 16 + qr + r;
                qkvb[(size_t)m * QKV_LD + n] = (u16)f2bf(acc[im][in][r] + bv);
            }
        }
}

// ------- V transpose: Vt[h][t][k] <- qkv[k][h*192+128+t] ------------------
__global__ __launch_bounds__(256) void transpose_v(const u16* __restrict__ qkvb,
                                                   u16* __restrict__ Vt)
{
    __shared__ u16 tile[64][72];
    const int h = blockIdx.y, k0 = blockIdx.x << 6;
    const int t = threadIdx.x;
    {
        int r = t >> 2, cg = (t & 3) << 4;
        const u16* src = qkvb + (size_t)(k0 + r) * QKV_LD + h * 192 + 128 + cg;
        *(uint4*)&tile[r][cg]     = *(const uint4*)src;
        *(uint4*)&tile[r][cg + 8] = *(const uint4*)(src + 8);
    }
    __syncthreads();
    {
        int c = t >> 2, kg = (t & 3) << 4;
        u16 tmp[16];
#pragma unroll
        for (int j = 0; j < 16; ++j) tmp[j] = tile[kg + j][c];
        u16* dst = Vt + ((size_t)h * 64 + c) * NT + k0 + kg;
        *(uint4*)dst       = *(uint4*)&tmp[0];
        *(uint4*)(dst + 8) = *(uint4*)&tmp[8];
    }
}

// ==== attn_pv: QK^T -> exp/z -> P@V (split-K=8), double-buffered loads ======
// Verbatim R7 (wave-private LDS, no barriers, register dbuf).
__global__ __launch_bounds__(512, 2) void attn_pv(
    const u16* __restrict__ qkvb, const u16* __restrict__ Vt,
    float* __restrict__ zpart, float* __restrict__ partsP)
{
    __shared__ u16 tile[8 * 2056];

    const int bid = blockIdx.x;
    const int zsp = bid & 7;
    const int qt  = bid >> 3;
    const int q0 = qt << 5;
    const int kbase = zsp << 8;

    const int t = threadIdx.x;
    const int w = t >> 6;              // wave = head
    const int lane = t & 63;
    const int fr = lane & 15;
    const int hi4 = lane >> 4;
    const int kd = hi4 << 3;
    const int qr = hi4 << 2;

    short8 aq[2][2];
#pragma unroll
    for (int mb = 0; mb < 2; ++mb)
#pragma unroll
        for (int kk = 0; kk < 2; ++kk)
            aq[mb][kk] = *(const short8*)(qkvb +
                (size_t)(q0 + mb * 16 + fr) * QKV_LD + w * 192 + kk * 32 + kd);

    v4f accP[2][4] = {};
    float zacc[2][4] = {};

    const u16* vsrc = Vt + (size_t)(w * 64 + fr) * NT + kd;
    const u16* ksrc = qkvb + (size_t)fr * QKV_LD + w * 192 + 64 + kd;

#define LOADCH(VB, BK, KC)                                                     \
    _Pragma("unroll")                                                          \
    for (int nt = 0; nt < 4; ++nt)                                             \
        _Pragma("unroll")                                                      \
        for (int kk = 0; kk < 2; ++kk) {                                       \
            VB[nt][kk] = *(const short8*)(vsrc + (size_t)nt * 16 * NT +        \
                                          (KC) + kk * 32);                     \
            BK[nt][kk] = *(const short8*)(ksrc + (size_t)((KC) + nt * 16) *    \
                                          QKV_LD + kk * 32);                   \
        }

#define COMPUTECH(VB, BK)                                                      \
    {                                                                          \
        v4f sacc[2][4] = {};                                                   \
        _Pragma("unroll")                                                      \
        for (int mb = 0; mb < 2; ++mb)                                         \
            _Pragma("unroll")                                                  \
            for (int nt = 0; nt < 4; ++nt) {                                   \
                sacc[mb][nt] = __builtin_amdgcn_mfma_f32_16x16x32_bf16(        \
                    aq[mb][0], BK[nt][0], sacc[mb][nt], 0, 0, 0);              \
                sacc[mb][nt] = __builtin_amdgcn_mfma_f32_16x16x32_bf16(        \
                    aq[mb][1], BK[nt][1], sacc[mb][nt], 0, 0, 0);              \
            }                                                                  \
        unsigned int pk[2][4][2];                                              \
        _Pragma("unroll")                                                      \
        for (int mb = 0; mb < 2; ++mb)                                         \
            _Pragma("unroll")                                                  \
            for (int nt = 0; nt < 4; ++nt)                                     \
                _Pragma("unroll")                                              \
                for (int r2 = 0; r2 < 2; ++r2) {                               \
                    float e0 = __expf(sacc[mb][nt][2 * r2] * 0.125f);          \
                    float e1 = __expf(sacc[mb][nt][2 * r2 + 1] * 0.125f);      \
                    zacc[mb][2 * r2] += e0;                                    \
                    zacc[mb][2 * r2 + 1] += e1;                                \
                    pk[mb][nt][r2] = cvtpk(e0, e1);                            \
                }                                                              \
        _Pragma("unroll")                                                      \
        for (int mb = 0; mb < 2; ++mb)                                         \
            _Pragma("unroll")                                                  \
            for (int nt = 0; nt < 4; ++nt) {                                   \
                const int kg = (nt << 1) + (fr >> 3);                          \
                _Pragma("unroll")                                              \
                for (int r = 0; r < 4; ++r) {                                  \
                    const int q = mb * 16 + qr + r;                            \
                    tile[w * 2056 + q * 64 + ((kg ^ (q & 7)) << 3) +           \
                         (fr & 7)] =                                           \
                        (u16)(pk[mb][nt][r >> 1] >> ((r & 1) << 4));           \
                }                                                              \
            }                                                                  \
        _Pragma("unroll")                                                      \
        for (int mb = 0; mb < 2; ++mb) {                                       \
            const int q = mb * 16 + fr;                                        \
            _Pragma("unroll")                                                  \
            for (int kk = 0; kk < 2; ++kk) {                                   \
                short8 ap = *(const short8*)&tile[w * 2056 + q * 64 +          \
                    (((kk * 4 + hi4) ^ (q & 7)) << 3)];                        \
                _Pragma("unroll")                                              \
                for (int nt = 0; nt < 4; ++nt)                                 \
                    accP[mb][nt] = __builtin_amdgcn_mfma_f32_16x16x32_bf16(    \
                        ap, VB[nt][kk], accP[mb][nt], 0, 0, 0);                \
            }                                                                  \
        }                                                                      \
    }

    short8 v0[4][2], b0[4][2], v1[4][2], b1[4][2];
    LOADCH(v0, b0, kbase)
#pragma unroll
    for (int cc = 0; cc < 2; ++cc) {
        LOADCH(v1, b1, kbase + ((2 * cc + 1) << 6))
        COMPUTECH(v0, b0)
        if (cc < 1) { LOADCH(v0, b0, kbase + ((2 * cc + 2) << 6)) }
        COMPUTECH(v1, b1)
    }
#undef LOADCH
#undef COMPUTECH

    // epilogue: z reduce + partial writes
#pragma unroll
    for (int off = 1; off < 16; off <<= 1)
#pragma unroll
        for (int mb = 0; mb < 2; ++mb)
#pragma unroll
            for (int r = 0; r < 4; ++r)
                zacc[mb][r] += __shfl_xor(zacc[mb][r], off);
    if (fr == 0) {
#pragma unroll
        for (int mb = 0; mb < 2; ++mb)
#pragma unroll
            for (int r = 0; r < 4; ++r)
                zpart[((size_t)zsp * 8 + w) * NT + q0 + mb * 16 + qr + r] = zacc[mb][r];
    }
    float* pP = partsP + (size_t)zsp * NT * EMBD;
#pragma unroll
    for (int mb = 0; mb < 2; ++mb)
#pragma unroll
        for (int nt = 0; nt < 4; ++nt)
#pragma unroll
            for (int r = 0; r < 4; ++r)
                pP[(size_t)(q0 + mb * 16 + qr + r) * EMBD +
                   (w << 6) + (nt << 4) + fr] = accP[mb][nt][r];
}

// ==== bias_v: angles -> sincos -> MFMA head-proj -> bias@V (split-K=8) ======
// R7 structure with 16-ROW q-tiles: grid 1024 (128 qt x 8 zsp). R7's grid of
// 512 was exactly 2 blocks/CU — residency was GRID-capped (VGPR 60 and LDS
// both allowed more). 16-row tiles double the grid -> 4 blocks/CU resident
// (LDS ~37.4KB x 4 = 150KB <= 160; VGPR drops with halved accB).
// partsB layout UNCHANGED (same 8 splits; blocks own disjoint 16-row ranges).
// Per-output op sequence & accumulation order verbatim -> bit-identical.
__global__ __launch_bounds__(512, 4) void bias_v(
    const u16* __restrict__ Vt, const float* __restrict__ vec,
    const float* __restrict__ Wb, const float* __restrict__ bb,
    float* __restrict__ partsB)
{
    __shared__ float flds[32];
    __shared__ float vql[48];
    __shared__ float ang[16 * 65];
    __shared__ u16 tile[8 * 2056];     // head stride 2056; 16 rows used

    const int bid = blockIdx.x;
    const int zsp = bid & 7;           // k-split == XCD
    const int qt  = bid >> 3;          // 0..127
    const int q0 = qt << 4;
    const int kbase = zsp << 8;

    const int t = threadIdx.x;
    const int w = t >> 6;              // wave = head
    const int lane = t & 63;
    const int fr = lane & 15;
    const int hi4 = lane >> 4;
    const int kd = hi4 << 3;
    const int qr = hi4 << 2;

    if (t < 32) flds[t] = __fdiv_rn(__fdiv_rn((float)t, 31.0f), 0.1f);
    else if (t < 80) vql[t - 32] = vec[q0 * 3 + (t - 32)];

    short8 BS, BC;
#pragma unroll
    for (int j = 0; j < 8; ++j) {
        float ws = (fr < 8) ? Wb[(kd + j) * 8 + fr] : 0.0f;
        float wc = (fr < 8) ? Wb[(32 + kd + j) * 8 + fr] : 0.0f;
        BS[j] = (short)f2bf(ws);
        BC[j] = (short)f2bf(wc);
    }
    const float bbv = (fr < 8) ? bb[fr] : 0.0f;

    v4f accB[4] = {};

    __syncthreads();

    for (int c = 0; c < 4; ++c) {
        const int kc = kbase + (c << 6);
        // ---- phase A: angles for 16x64 pairs, 2/thread (frozen numerics)
        {
            const int p0 = t << 1;
            const int q = p0 >> 6;         // 0..15
            const int kl = p0 & 63;
            const float a0 = vql[q * 3], a1 = vql[q * 3 + 1], a2 = vql[q * 3 + 2];
            const float* vk = vec + (size_t)(kc + kl) * 3;
#pragma unroll
            for (int j = 0; j < 2; ++j) {
                float c0 = vk[j * 3], c1 = vk[j * 3 + 1], c2 = vk[j * 3 + 2];
                float dot = __fadd_rn(__fadd_rn(__fmul_rn(a0, c0), __fmul_rn(a1, c1)),
                                      __fmul_rn(a2, c2));
                float dotc = fminf(fmaxf(dot, 0.0f), 1.0f);
                ang[q * 65 + kl + j] = __fdiv_rn(acosf(dotc), 0.001f);
            }
        }
        __syncthreads();
        // ---- phase B: sincos features -> MFMA projection -> bias tile
#pragma unroll
        for (int gi = 0; gi < 8; ++gi) {
            const int g = w + (gi << 3);   // 0..63
            const int q = g >> 2;          // 0..15
            const int ksub = (g & 3) << 4;
            const float av = ang[q * 65 + ksub + fr];
            float sv[8], cv[8];
#pragma unroll
            for (int j = 0; j < 8; ++j) {
                float ph = __fmul_rn(flds[kd + j], av);
                float rv = ph * 0.15915494309189535f;
                float rf = rv - floorf(rv);
                sv[j] = __builtin_amdgcn_sinf(rf);
                cv[j] = __builtin_amdgcn_cosf(rf);
            }
            union { uint4 u; short8 v; } As, Ac;
            As.u.x = cvtpk(sv[0], sv[1]); As.u.y = cvtpk(sv[2], sv[3]);
            As.u.z = cvtpk(sv[4], sv[5]); As.u.w = cvtpk(sv[6], sv[7]);
            Ac.u.x = cvtpk(cv[0], cv[1]); Ac.u.y = cvtpk(cv[2], cv[3]);
            Ac.u.z = cvtpk(cv[4], cv[5]); Ac.u.w = cvtpk(cv[6], cv[7]);
            v4f cb = {};
            cb = __builtin_amdgcn_mfma_f32_16x16x32_bf16(As.v, BS, cb, 0, 0, 0);
            cb = __builtin_amdgcn_mfma_f32_16x16x32_bf16(Ac.v, BC, cb, 0, 0, 0);
            if (fr < 8) {
                const int kg = (ksub + qr) >> 3;
                uint2 wv;
                wv.x = cvtpk(cb[0] + bbv, cb[1] + bbv);
                wv.y = cvtpk(cb[2] + bbv, cb[3] + bbv);
                *(uint2*)&tile[fr * 2056 + q * 64 + ((kg ^ (q & 7)) << 3) + (qr & 7)] = wv;
            }
        }
        __syncthreads();
        // ---- phase C: accB += bias@V (accum order per element verbatim)
#pragma unroll
        for (int kk = 0; kk < 2; ++kk) {
            const int q0l = fr;
            short8 ab0 = *(const short8*)&tile[w * 2056 + q0l * 64 +
                (((kk * 4 + hi4) ^ (q0l & 7)) << 3)];
#pragma unroll
            for (int nt = 0; nt < 4; ++nt) {
                short8 vbx = *(const short8*)(Vt +
                    (size_t)(w * 64 + nt * 16 + fr) * NT + kc + kk * 32 + kd);
                accB[nt] = __builtin_amdgcn_mfma_f32_16x16x32_bf16(ab0, vbx, accB[nt], 0, 0, 0);
            }
        }
        // next-iteration hazards covered by the two barriers above (R5 note)
    }
    float* pB = partsB + (size_t)zsp * NT * EMBD;
#pragma unroll
    for (int nt = 0; nt < 4; ++nt)
#pragma unroll
        for (int r = 0; r < 4; ++r)
            pB[(size_t)(q0 + qr + r) * EMBD +
               (w << 6) + (nt << 4) + fr] = accB[nt][r];
}

// ------- reduce 8 partials: y = sumP/sumZ + sumB -> bf16 hi/lo --------------
__global__ __launch_bounds__(256) void reduce_y2(const float* __restrict__ partsP,
    const float* __restrict__ partsB, const float* __restrict__ zpart,
    u16* __restrict__ yh, u16* __restrict__ yl)
{
    const int MN = NT * EMBD;
    int i = (blockIdx.x * 256 + threadIdx.x) << 2;
    const int q = i >> 9;
    const int h = (i & 511) >> 6;
    float zs = 0.0f;
#pragma unroll
    for (int z = 0; z < KSPLIT; ++z) zs += zpart[((size_t)z * 8 + h) * NT + q];
    float4 aP = *(const float4*)(partsP + i);
    float4 aB = *(const float4*)(partsB + i);
#pragma unroll
    for (int z = 1; z < KSPLIT; ++z) {
        float4 p = *(const float4*)(partsP + (size_t)z * MN + i);
        float4 b = *(const float4*)(partsB + (size_t)z * MN + i);
        aP.x += p.x; aP.y += p.y; aP.z += p.z; aP.w += p.w;
        aB.x += b.x; aB.y += b.y; aB.z += b.z; aB.w += b.w;
    }
    const float iz = 1.0f / zs;
    float f[4] = {aP.x * iz + aB.x, aP.y * iz + aB.y,
                  aP.z * iz + aB.z, aP.w * iz + aB.w};
    unsigned int hi[4], lo[4];
#pragma unroll
    for (int j = 0; j < 4; ++j) {
        hi[j] = f2bf(f[j]);
        lo[j] = f2bf(f[j] - bf2f(hi[j]));
    }
    uint2 wh; wh.x = hi[0] | (hi[1] << 16); wh.y = hi[2] | (hi[3] << 16);
    uint2 wl; wl.x = lo[0] | (lo[1] << 16); wl.y = lo[2] | (lo[3] << 16);
    *(uint2*)(yh + i) = wh;
    *(uint2*)(yl + i) = wl;
}

// ------- out = y @ Wout + bout via split-precision bf16 MFMA ----------------
__global__ __launch_bounds__(256) void gemm_out_mfma(const u16* __restrict__ yh,
    const u16* __restrict__ yl, const u16* __restrict__ wh,
    const u16* __restrict__ wl, const float* __restrict__ bias,
    float* __restrict__ out)
{
    const int n0 = blockIdx.x << 6, m0 = blockIdx.y << 6;
    const int w = threadIdx.x >> 6, lane = threadIdx.x & 63;
    const int wm = w >> 1, wn = w & 1;
    const int fr = lane & 15, kd = (lane >> 4) << 3;

    const u16* ah0 = yh + (size_t)(m0 + wm * 32 + fr) * EMBD + kd;
    const u16* al0 = yl + (size_t)(m0 + wm * 32 + fr) * EMBD + kd;
    const u16* bh0 = wh + (size_t)(n0 + wn * 32 + fr) * EMBD + kd;
    const u16* bl0 = wl + (size_t)(n0 + wn * 32 + fr) * EMBD + kd;

    v4f acc[2][2] = {};
    for (int kc = 0; kc < EMBD; kc += 32) {
        short8 a_h[2], a_l[2], b_h[2], b_l[2];
#pragma unroll
        for (int im = 0; im < 2; ++im) {
            a_h[im] = *(const short8*)(ah0 + (size_t)im * 16 * EMBD + kc);
            a_l[im] = *(const short8*)(al0 + (size_t)im * 16 * EMBD + kc);
        }
#pragma unroll
        for (int in = 0; in < 2; ++in) {
            b_h[in] = *(const short8*)(bh0 + (size_t)in * 16 * EMBD + kc);
            b_l[in] = *(const short8*)(bl0 + (size_t)in * 16 * EMBD + kc);
        }
#pragma unroll
        for (int im = 0; im < 2; ++im)
#pragma unroll
            for (int in = 0; in < 2; ++in) {
                acc[im][in] = __builtin_amdgcn_mfma_f32_16x16x32_bf16(a_h[im], b_h[in], acc[im][in], 0, 0, 0);
                acc[im][in] = __builtin_amdgcn_mfma_f32_16x16x32_bf16(a_h[im], b_l[in], acc[im][in], 0, 0, 0);
                acc[im][in] = __builtin_amdgcn_mfma_f32_16x16x32_bf16(a_l[im], b_h[in], acc[im][in], 0, 0, 0);
            }
    }
    const int qr = (lane >> 4) << 2;
#pragma unroll
    for (int im = 0; im < 2; ++im)
#pragma unroll
        for (int in = 0; in < 2; ++in) {
            int n = n0 + wn * 32 + in * 16 + fr;
            float bv = bias[n];
#pragma unroll
            for (int r = 0; r < 4; ++r) {
                int m = m0 + wm * 32 + im * 16 + qr + r;
                out[(size_t)m * EMBD + n] = acc[im][in][r] + bv;
            }
        }
}

extern "C" void kernel_launch(void* const* d_in, const int* in_sizes, int n_in,
                              void* d_out, int out_size, void* d_ws, size_t ws_size,
                              hipStream_t stream)
{
    const float* x    = (const float*)d_in[0];
    const float* vec  = (const float*)d_in[1];
    const float* Wqkv = (const float*)d_in[2];
    const float* bqkv = (const float*)d_in[3];
    const float* Wb   = (const float*)d_in[4];
    const float* bb   = (const float*)d_in[5];
    const float* Wout = (const float*)d_in[6];
    const float* bout = (const float*)d_in[7];
    float* out = (float*)d_out;

    char* ws = (char*)d_ws;
    u16*   qkvb   = (u16*)(ws);                     //  6,291,456
    u16*   Vt     = (u16*)(ws + 6291456);           //  2,097,152
    float* zpart  = (float*)(ws + 8388608);         //    524,288 (8*8*2048*4)
    float* partsP = (float*)(ws + 8912896);         // 33,554,432
    float* partsB = (float*)(ws + 42467328);        // 33,554,432
    u16*   yh     = (u16*)(ws + 76021760);          //  2,097,152
    u16*   yl     = (u16*)(ws + 78118912);          //  2,097,152
    u16*   xh     = (u16*)(ws + 80216064);          //  2,097,152
    u16*   xl     = (u16*)(ws + 82313216);          //  2,097,152
    u16*   wth    = (u16*)(ws + 84410368);          //  1,572,864
    u16*   wtl    = (u16*)(ws + 85983232);          //  1,572,864
    u16*   woth   = (u16*)(ws + 87556096);          //    524,288
    u16*   wotl   = (u16*)(ws + 88080384);          //    524,288
    // total: 88,604,672 B

    prep<<<1280, 256, 0, stream>>>(x, xh, xl, Wqkv, wth, wtl, Wout, woth, wotl);
    gemm_qkv_mfma<<<dim3(24, 32), 256, 0, stream>>>(xh, xl, wth, wtl, bqkv, qkvb);
    transpose_v<<<dim3(32, 8), 256, 0, stream>>>(qkvb, Vt);
    bias_v<<<128 * KSPLIT, 512, 0, stream>>>(Vt, vec, Wb, bb, partsB);
    attn_pv<<<64 * KSPLIT, 512, 0, stream>>>(qkvb, Vt, zpart, partsP);
    reduce_y2<<<1024, 256, 0, stream>>>(partsP, partsB, zpart, yh, yl);
    gemm_out_mfma<<<dim3(8, 32), 256, 0, stream>>>(yh, yl, woth, wotl, bout, out);
}

// Round 9
// 248.113 us; speedup vs baseline: 1.0284x; 1.0284x over previous
//
#include <hip/hip_runtime.h>
#include <hip/hip_bf16.h>
#include <math.h>

#define NT 2048
#define EMBD 512
#define NH 8
#define QKV_LD 1536
#define KSPLIT 8

typedef unsigned short u16;
typedef __attribute__((ext_vector_type(8))) short short8;
typedef __attribute__((ext_vector_type(4))) float v4f;

static __device__ __forceinline__ float bf2f(unsigned int u) {
    union { unsigned int i; float f; } c; c.i = u << 16; return c.f;
}
static __device__ __forceinline__ unsigned int f2bf(float x) {   // RNE
    union { float f; unsigned int u; } c; c.f = x;
    return (c.u + 0x7fffu + ((c.u >> 16) & 1u)) >> 16;
}
// HW packed f32->bf16 (RNE, bit-identical to f2bf pair) — one inst per pair
static __device__ __forceinline__ unsigned int cvtpk(float lo, float hi) {
    unsigned int r;
    asm("v_cvt_pk_bf16_f32 %0, %1, %2" : "=v"(r) : "v"(lo), "v"(hi));
    return r;
}

// ------- prep: split x (hi/lo) + split+transpose Wqkv and Wout --------------
__global__ __launch_bounds__(256) void prep(const float* __restrict__ x,
    u16* __restrict__ xh, u16* __restrict__ xl,
    const float* __restrict__ Wqkv, u16* __restrict__ wth, u16* __restrict__ wtl,
    const float* __restrict__ Wout, u16* __restrict__ woth, u16* __restrict__ wotl)
{
    __shared__ float tile[64][65];
    int b = blockIdx.x;
    const int t = threadIdx.x;
    if (b < 1024) {                       // ---- split_x region
        int i = (b * 256 + t) << 2;
        float4 v = *(const float4*)(x + i);
        float f[4] = {v.x, v.y, v.z, v.w};
        unsigned int hi[4], lo[4];
#pragma unroll
        for (int j = 0; j < 4; ++j) {
            hi[j] = f2bf(f[j]);
            lo[j] = f2bf(f[j] - bf2f(hi[j]));
        }
        uint2 wh; wh.x = hi[0] | (hi[1] << 16); wh.y = hi[2] | (hi[3] << 16);
        uint2 wl; wl.x = lo[0] | (lo[1] << 16); wl.y = lo[2] | (lo[3] << 16);
        *(uint2*)(xh + i) = wh;
        *(uint2*)(xl + i) = wl;
        return;
    }
    b -= 1024;                            // ---- split_wt regions
    const float* W; u16* th; u16* tl; int ld, bx, by;
    if (b < 192) { W = Wqkv; th = wth;  tl = wtl;  ld = QKV_LD; bx = b % 24; by = b / 24; }
    else { b -= 192; W = Wout; th = woth; tl = wotl; ld = EMBD; bx = b & 7; by = b >> 3; }
    const int n0 = bx << 6, k0 = by << 6;
    const int r = t >> 2, c4 = (t & 3) << 4;
#pragma unroll
    for (int j = 0; j < 4; ++j)
        *(float4*)&tile[r][c4 + (j << 2)] =
            *(const float4*)(W + (size_t)(k0 + r) * ld + n0 + c4 + (j << 2));
    __syncthreads();
    const int n_l = t >> 2;
    u16 vh[16], vl[16];
#pragma unroll
    for (int j = 0; j < 16; ++j) {
        float f = tile[c4 + j][n_l];
        unsigned int h = f2bf(f);
        vh[j] = (u16)h;
        vl[j] = (u16)f2bf(f - bf2f(h));
    }
    u16* dh = th + (size_t)(n0 + n_l) * EMBD + k0 + c4;
    u16* dl = tl + (size_t)(n0 + n_l) * EMBD + k0 + c4;
    *(uint4*)dh       = *(uint4*)&vh[0];
    *(uint4*)(dh + 8) = *(uint4*)&vh[8];
    *(uint4*)dl       = *(uint4*)&vl[0];
    *(uint4*)(dl + 8) = *(uint4*)&vl[8];
}

// ------- qkv = x @ Wqkv + b via split-precision bf16 MFMA -------------------
// Epilogue also writes V columns TRANSPOSED to Vt (replaces transpose_v):
// V cols for head h are n in [192h+128, 192h+192) = exactly n-block bx=3h+2.
// Stored value is the identical bf16 -> Vt bit-identical to transpose_v's.
__global__ __launch_bounds__(256) void gemm_qkv_mfma(const u16* __restrict__ xh,
    const u16* __restrict__ xl, const u16* __restrict__ wth,
    const u16* __restrict__ wtl, const float* __restrict__ bias,
    u16* __restrict__ qkvb, u16* __restrict__ Vt)
{
    const int bx = blockIdx.x;
    const int n0 = bx << 6, m0 = blockIdx.y << 6;
    const int w = threadIdx.x >> 6, lane = threadIdx.x & 63;
    const int wm = w >> 1, wn = w & 1;
    const int fr = lane & 15, kd = (lane >> 4) << 3;

    const u16* ah0 = xh + (size_t)(m0 + wm * 32 + fr) * EMBD + kd;
    const u16* al0 = xl + (size_t)(m0 + wm * 32 + fr) * EMBD + kd;
    const u16* bh0 = wth + (size_t)(n0 + wn * 32 + fr) * EMBD + kd;
    const u16* bl0 = wtl + (size_t)(n0 + wn * 32 + fr) * EMBD + kd;

    v4f acc[2][2] = {};
    for (int kc = 0; kc < EMBD; kc += 32) {
        short8 a_h[2], a_l[2], b_h[2], b_l[2];
#pragma unroll
        for (int im = 0; im < 2; ++im) {
            a_h[im] = *(const short8*)(ah0 + (size_t)im * 16 * EMBD + kc);
            a_l[im] = *(const short8*)(al0 + (size_t)im * 16 * EMBD + kc);
        }
#pragma unroll
        for (int in = 0; in < 2; ++in) {
            b_h[in] = *(const short8*)(bh0 + (size_t)in * 16 * EMBD + kc);
            b_l[in] = *(const short8*)(bl0 + (size_t)in * 16 * EMBD + kc);
        }
#pragma unroll
        for (int im = 0; im < 2; ++im)
#pragma unroll
            for (int in = 0; in < 2; ++in) {
                acc[im][in] = __builtin_amdgcn_mfma_f32_16x16x32_bf16(a_h[im], b_h[in], acc[im][in], 0, 0, 0);
                acc[im][in] = __builtin_amdgcn_mfma_f32_16x16x32_bf16(a_h[im], b_l[in], acc[im][in], 0, 0, 0);
                acc[im][in] = __builtin_amdgcn_mfma_f32_16x16x32_bf16(a_l[im], b_h[in], acc[im][in], 0, 0, 0);
            }
    }
    const int qr = (lane >> 4) << 2;
    const int isv = ((bx % 3) == 2);
    const int h = bx / 3;
#pragma unroll
    for (int im = 0; im < 2; ++im)
#pragma unroll
        for (int in = 0; in < 2; ++in) {
            int nl = wn * 32 + in * 16 + fr;
            int n = n0 + nl;
            float bv = bias[n];
#pragma unroll
            for (int r = 0; r < 4; ++r) {
                int m = m0 + wm * 32 + im * 16 + qr + r;
                u16 val = (u16)f2bf(acc[im][in][r] + bv);
                qkvb[(size_t)m * QKV_LD + n] = val;
                if (isv)
                    Vt[((size_t)h * 64 + nl) * NT + m] = val;
            }
        }
}

// ==== attn_pv: QK^T -> exp/z -> P@V (split-K=8), double-buffered loads ======
// Verbatim R7 (wave-private LDS, no barriers, register dbuf).
__global__ __launch_bounds__(512, 2) void attn_pv(
    const u16* __restrict__ qkvb, const u16* __restrict__ Vt,
    float* __restrict__ zpart, float* __restrict__ partsP)
{
    __shared__ u16 tile[8 * 2056];

    const int bid = blockIdx.x;
    const int zsp = bid & 7;
    const int qt  = bid >> 3;
    const int q0 = qt << 5;
    const int kbase = zsp << 8;

    const int t = threadIdx.x;
    const int w = t >> 6;              // wave = head
    const int lane = t & 63;
    const int fr = lane & 15;
    const int hi4 = lane >> 4;
    const int kd = hi4 << 3;
    const int qr = hi4 << 2;

    short8 aq[2][2];
#pragma unroll
    for (int mb = 0; mb < 2; ++mb)
#pragma unroll
        for (int kk = 0; kk < 2; ++kk)
            aq[mb][kk] = *(const short8*)(qkvb +
                (size_t)(q0 + mb * 16 + fr) * QKV_LD + w * 192 + kk * 32 + kd);

    v4f accP[2][4] = {};
    float zacc[2][4] = {};

    const u16* vsrc = Vt + (size_t)(w * 64 + fr) * NT + kd;
    const u16* ksrc = qkvb + (size_t)fr * QKV_LD + w * 192 + 64 + kd;

#define LOADCH(VB, BK, KC)                                                     \
    _Pragma("unroll")                                                          \
    for (int nt = 0; nt < 4; ++nt)                                             \
        _Pragma("unroll")                                                      \
        for (int kk = 0; kk < 2; ++kk) {                                       \
            VB[nt][kk] = *(const short8*)(vsrc + (size_t)nt * 16 * NT +        \
                                          (KC) + kk * 32);                     \
            BK[nt][kk] = *(const short8*)(ksrc + (size_t)((KC) + nt * 16) *    \
                                          QKV_LD + kk * 32);                   \
        }

#define COMPUTECH(VB, BK)                                                      \
    {                                                                          \
        v4f sacc[2][4] = {};                                                   \
        _Pragma("unroll")                                                      \
        for (int mb = 0; mb < 2; ++mb)                                         \
            _Pragma("unroll")                                                  \
            for (int nt = 0; nt < 4; ++nt) {                                   \
                sacc[mb][nt] = __builtin_amdgcn_mfma_f32_16x16x32_bf16(        \
                    aq[mb][0], BK[nt][0], sacc[mb][nt], 0, 0, 0);              \
                sacc[mb][nt] = __builtin_amdgcn_mfma_f32_16x16x32_bf16(        \
                    aq[mb][1], BK[nt][1], sacc[mb][nt], 0, 0, 0);              \
            }                                                                  \
        unsigned int pk[2][4][2];                                              \
        _Pragma("unroll")                                                      \
        for (int mb = 0; mb < 2; ++mb)                                         \
            _Pragma("unroll")                                                  \
            for (int nt = 0; nt < 4; ++nt)                                     \
                _Pragma("unroll")                                              \
                for (int r2 = 0; r2 < 2; ++r2) {                               \
                    float e0 = __expf(sacc[mb][nt][2 * r2] * 0.125f);          \
                    float e1 = __expf(sacc[mb][nt][2 * r2 + 1] * 0.125f);      \
                    zacc[mb][2 * r2] += e0;                                    \
                    zacc[mb][2 * r2 + 1] += e1;                                \
                    pk[mb][nt][r2] = cvtpk(e0, e1);                            \
                }                                                              \
        _Pragma("unroll")                                                      \
        for (int mb = 0; mb < 2; ++mb)                                         \
            _Pragma("unroll")                                                  \
            for (int nt = 0; nt < 4; ++nt) {                                   \
                const int kg = (nt << 1) + (fr >> 3);                          \
                _Pragma("unroll")                                              \
                for (int r = 0; r < 4; ++r) {                                  \
                    const int q = mb * 16 + qr + r;                            \
                    tile[w * 2056 + q * 64 + ((kg ^ (q & 7)) << 3) +           \
                         (fr & 7)] =                                           \
                        (u16)(pk[mb][nt][r >> 1] >> ((r & 1) << 4));           \
                }                                                              \
            }                                                                  \
        _Pragma("unroll")                                                      \
        for (int mb = 0; mb < 2; ++mb) {                                       \
            const int q = mb * 16 + fr;                                        \
            _Pragma("unroll")                                                  \
            for (int kk = 0; kk < 2; ++kk) {                                   \
                short8 ap = *(const short8*)&tile[w * 2056 + q * 64 +          \
                    (((kk * 4 + hi4) ^ (q & 7)) << 3)];                        \
                _Pragma("unroll")                                              \
                for (int nt = 0; nt < 4; ++nt)                                 \
                    accP[mb][nt] = __builtin_amdgcn_mfma_f32_16x16x32_bf16(    \
                        ap, VB[nt][kk], accP[mb][nt], 0, 0, 0);                \
            }                                                                  \
        }                                                                      \
    }

    short8 v0[4][2], b0[4][2], v1[4][2], b1[4][2];
    LOADCH(v0, b0, kbase)
#pragma unroll
    for (int cc = 0; cc < 2; ++cc) {
        LOADCH(v1, b1, kbase + ((2 * cc + 1) << 6))
        COMPUTECH(v0, b0)
        if (cc < 1) { LOADCH(v0, b0, kbase + ((2 * cc + 2) << 6)) }
        COMPUTECH(v1, b1)
    }
#undef LOADCH
#undef COMPUTECH

    // epilogue: z reduce + partial writes
#pragma unroll
    for (int off = 1; off < 16; off <<= 1)
#pragma unroll
        for (int mb = 0; mb < 2; ++mb)
#pragma unroll
            for (int r = 0; r < 4; ++r)
                zacc[mb][r] += __shfl_xor(zacc[mb][r], off);
    if (fr == 0) {
#pragma unroll
        for (int mb = 0; mb < 2; ++mb)
#pragma unroll
            for (int r = 0; r < 4; ++r)
                zpart[((size_t)zsp * 8 + w) * NT + q0 + mb * 16 + qr + r] = zacc[mb][r];
    }
    float* pP = partsP + (size_t)zsp * NT * EMBD;
#pragma unroll
    for (int mb = 0; mb < 2; ++mb)
#pragma unroll
        for (int nt = 0; nt < 4; ++nt)
#pragma unroll
            for (int r = 0; r < 4; ++r)
                pP[(size_t)(q0 + mb * 16 + qr + r) * EMBD +
                   (w << 6) + (nt << 4) + fr] = accP[mb][nt][r];
}

// ==== bias_v: angles -> sincos -> MFMA head-proj -> bias@V (split-K=8) ======
// R7 geometry (32-row q-tiles, grid 512) restructured for minimal barriers:
//  - phase A is WAVE-PRIVATE: wave w consumes exactly the angles for
//    g = w + 8*gi (disjoint 256-angle set) -> computes them into its own
//    angw strip; no A<->B barrier (same-wave LDS ordering).
//  - bias tile DOUBLE-BUFFERED -> no C->B(next) barrier; only the real
//    cross-wave B->C handoff keeps a barrier (1/chunk, 4 total vs R7's 9).
//  - flds -> per-lane registers, vql dropped (vec is L1-resident 24KB);
//    identical op sequences on identical inputs -> angles, bias tile, accB
//    all bit-identical to R7. LDS 74KB -> 2 blocks/CU (128KB precedent OK).
__global__ __launch_bounds__(512, 4) void bias_v(
    const u16* __restrict__ Vt, const float* __restrict__ vec,
    const float* __restrict__ Wb, const float* __restrict__ bb,
    float* __restrict__ partsB)
{
    __shared__ float angw[8 * 260];       // per-wave 256 angles (+4 pad)
    __shared__ u16 tile[2][8 * 2056];     // double-buffered bias tile

    const int bid = blockIdx.x;
    const int zsp = bid & 7;
    const int qt  = bid >> 3;
    const int q0 = qt << 5;
    const int kbase = zsp << 8;

    const int t = threadIdx.x;
    const int w = t >> 6;              // wave = head
    const int lane = t & 63;
    const int fr = lane & 15;
    const int hi4 = lane >> 4;
    const int kd = hi4 << 3;
    const int qr = hi4 << 2;

    // freqs in registers (identical ops to old flds[] -> identical bits)
    float fl[8];
#pragma unroll
    for (int j = 0; j < 8; ++j)
        fl[j] = __fdiv_rn(__fdiv_rn((float)(kd + j), 31.0f), 0.1f);

    short8 BS, BC;
#pragma unroll
    for (int j = 0; j < 8; ++j) {
        float ws = (fr < 8) ? Wb[(kd + j) * 8 + fr] : 0.0f;
        float wc = (fr < 8) ? Wb[(32 + kd + j) * 8 + fr] : 0.0f;
        BS[j] = (short)f2bf(ws);
        BC[j] = (short)f2bf(wc);
    }
    const float bbv = (fr < 8) ? bb[fr] : 0.0f;

    v4f accB[2][4] = {};

#pragma unroll
    for (int c = 0; c < 4; ++c) {
        const int kc = kbase + (c << 6);
        u16* tp = tile[c & 1];
        // ---- phase A (wave-private): 4 angles/lane, frozen numerics
        {
#pragma unroll
            for (int jj = 0; jj < 4; ++jj) {
                const int idx = (lane << 2) + jj;       // 0..255
                const int gi = idx >> 4;
                const int g = w + (gi << 3);
                const int q = g >> 2;                   // 0..31
                const int kl = ((g & 3) << 4) + (idx & 15);
                const float* vq = vec + (size_t)(q0 + q) * 3;
                const float* vk = vec + (size_t)(kc + kl) * 3;
                float a0 = vq[0], a1 = vq[1], a2 = vq[2];
                float c0 = vk[0], c1 = vk[1], c2 = vk[2];
                float dot = __fadd_rn(__fadd_rn(__fmul_rn(a0, c0), __fmul_rn(a1, c1)),
                                      __fmul_rn(a2, c2));
                float dotc = fminf(fmaxf(dot, 0.0f), 1.0f);
                angw[w * 260 + idx] = __fdiv_rn(acosf(dotc), 0.001f);
            }
        }
        // (no barrier: wave w reads only angw[w*260..] below)
        // ---- phase B: sincos features -> MFMA projection -> bias tile
#pragma unroll
        for (int gi = 0; gi < 16; ++gi) {
            const int g = w + (gi << 3);
            const int q = g >> 2;
            const int ksub = (g & 3) << 4;
            const float av = angw[w * 260 + (gi << 4) + fr];
            float sv[8], cv[8];
#pragma unroll
            for (int j = 0; j < 8; ++j) {
                float ph = __fmul_rn(fl[j], av);
                float rv = ph * 0.15915494309189535f;
                float rf = rv - floorf(rv);
                sv[j] = __builtin_amdgcn_sinf(rf);
                cv[j] = __builtin_amdgcn_cosf(rf);
            }
            union { uint4 u; short8 v; } As, Ac;
            As.u.x = cvtpk(sv[0], sv[1]); As.u.y = cvtpk(sv[2], sv[3]);
            As.u.z = cvtpk(sv[4], sv[5]); As.u.w = cvtpk(sv[6], sv[7]);
            Ac.u.x = cvtpk(cv[0], cv[1]); Ac.u.y = cvtpk(cv[2], cv[3]);
            Ac.u.z = cvtpk(cv[4], cv[5]); Ac.u.w = cvtpk(cv[6], cv[7]);
            v4f cb = {};
            cb = __builtin_amdgcn_mfma_f32_16x16x32_bf16(As.v, BS, cb, 0, 0, 0);
            cb = __builtin_amdgcn_mfma_f32_16x16x32_bf16(Ac.v, BC, cb, 0, 0, 0);
            if (fr < 8) {
                const int kg = (ksub + qr) >> 3;
                uint2 wv;
                wv.x = cvtpk(cb[0] + bbv, cb[1] + bbv);
                wv.y = cvtpk(cb[2] + bbv, cb[3] + bbv);
                *(uint2*)&tp[fr * 2056 + q * 64 + ((kg ^ (q & 7)) << 3) + (qr & 7)] = wv;
            }
        }
        __syncthreads();   // the one real cross-wave handoff (B -> C)
        // ---- phase C: accB += bias@V (accum order verbatim R7)
#pragma unroll
        for (int kk = 0; kk < 2; ++kk) {
            const int q0l = 0 * 16 + fr, q1l = 1 * 16 + fr;
            short8 ab0 = *(const short8*)&tp[w * 2056 + q0l * 64 +
                (((kk * 4 + hi4) ^ (q0l & 7)) << 3)];
            short8 ab1 = *(const short8*)&tp[w * 2056 + q1l * 64 +
                (((kk * 4 + hi4) ^ (q1l & 7)) << 3)];
#pragma unroll
            for (int nt = 0; nt < 4; ++nt) {
                short8 vbx = *(const short8*)(Vt +
                    (size_t)(w * 64 + nt * 16 + fr) * NT + kc + kk * 32 + kd);
                accB[0][nt] = __builtin_amdgcn_mfma_f32_16x16x32_bf16(ab0, vbx, accB[0][nt], 0, 0, 0);
                accB[1][nt] = __builtin_amdgcn_mfma_f32_16x16x32_bf16(ab1, vbx, accB[1][nt], 0, 0, 0);
            }
        }
        // C(c) vs B(c+2) on the same buffer is ordered by the barrier at
        // chunk c+1 (each wave's B(c+1) follows its C(c) in program order).
    }
    float* pB = partsB + (size_t)zsp * NT * EMBD;
#pragma unroll
    for (int mb = 0; mb < 2; ++mb)
#pragma unroll
        for (int nt = 0; nt < 4; ++nt)
#pragma unroll
            for (int r = 0; r < 4; ++r)
                pB[(size_t)(q0 + mb * 16 + qr + r) * EMBD +
                   (w << 6) + (nt << 4) + fr] = accB[mb][nt][r];
}

// ------- reduce 8 partials: y = sumP/sumZ + sumB -> bf16 hi/lo --------------
__global__ __launch_bounds__(256) void reduce_y2(const float* __restrict__ partsP,
    const float* __restrict__ partsB, const float* __restrict__ zpart,
    u16* __restrict__ yh, u16* __restrict__ yl)
{
    const int MN = NT * EMBD;
    int i = (blockIdx.x * 256 + threadIdx.x) << 2;
    const int q = i >> 9;
    const int h = (i & 511) >> 6;
    float zs = 0.0f;
#pragma unroll
    for (int z = 0; z < KSPLIT; ++z) zs += zpart[((size_t)z * 8 + h) * NT + q];
    float4 aP = *(const float4*)(partsP + i);
    float4 aB = *(const float4*)(partsB + i);
#pragma unroll
    for (int z = 1; z < KSPLIT; ++z) {
        float4 p = *(const float4*)(partsP + (size_t)z * MN + i);
        float4 b = *(const float4*)(partsB + (size_t)z * MN + i);
        aP.x += p.x; aP.y += p.y; aP.z += p.z; aP.w += p.w;
        aB.x += b.x; aB.y += b.y; aB.z += b.z; aB.w += b.w;
    }
    const float iz = 1.0f / zs;
    float f[4] = {aP.x * iz + aB.x, aP.y * iz + aB.y,
                  aP.z * iz + aB.z, aP.w * iz + aB.w};
    unsigned int hi[4], lo[4];
#pragma unroll
    for (int j = 0; j < 4; ++j) {
        hi[j] = f2bf(f[j]);
        lo[j] = f2bf(f[j] - bf2f(hi[j]));
    }
    uint2 wh; wh.x = hi[0] | (hi[1] << 16); wh.y = hi[2] | (hi[3] << 16);
    uint2 wl; wl.x = lo[0] | (lo[1] << 16); wl.y = lo[2] | (lo[3] << 16);
    *(uint2*)(yh + i) = wh;
    *(uint2*)(yl + i) = wl;
}

// ------- out = y @ Wout + bout via split-precision bf16 MFMA ----------------
__global__ __launch_bounds__(256) void gemm_out_mfma(const u16* __restrict__ yh,
    const u16* __restrict__ yl, const u16* __restrict__ wh,
    const u16* __restrict__ wl, const float* __restrict__ bias,
    float* __restrict__ out)
{
    const int n0 = blockIdx.x << 6, m0 = blockIdx.y << 6;
    const int w = threadIdx.x >> 6, lane = threadIdx.x & 63;
    const int wm = w >> 1, wn = w & 1;
    const int fr = lane & 15, kd = (lane >> 4) << 3;

    const u16* ah0 = yh + (size_t)(m0 + wm * 32 + fr) * EMBD + kd;
    const u16* al0 = yl + (size_t)(m0 + wm * 32 + fr) * EMBD + kd;
    const u16* bh0 = wh + (size_t)(n0 + wn * 32 + fr) * EMBD + kd;
    const u16* bl0 = wl + (size_t)(n0 + wn * 32 + fr) * EMBD + kd;

    v4f acc[2][2] = {};
    for (int kc = 0; kc < EMBD; kc += 32) {
        short8 a_h[2], a_l[2], b_h[2], b_l[2];
#pragma unroll
        for (int im = 0; im < 2; ++im) {
            a_h[im] = *(const short8*)(ah0 + (size_t)im * 16 * EMBD + kc);
            a_l[im] = *(const short8*)(al0 + (size_t)im * 16 * EMBD + kc);
        }
#pragma unroll
        for (int in = 0; in < 2; ++in) {
            b_h[in] = *(const short8*)(bh0 + (size_t)in * 16 * EMBD + kc);
            b_l[in] = *(const short8*)(bl0 + (size_t)in * 16 * EMBD + kc);
        }
#pragma unroll
        for (int im = 0; im < 2; ++im)
#pragma unroll
            for (int in = 0; in < 2; ++in) {
                acc[im][in] = __builtin_amdgcn_mfma_f32_16x16x32_bf16(a_h[im], b_h[in], acc[im][in], 0, 0, 0);
                acc[im][in] = __builtin_amdgcn_mfma_f32_16x16x32_bf16(a_h[im], b_l[in], acc[im][in], 0, 0, 0);
                acc[im][in] = __builtin_amdgcn_mfma_f32_16x16x32_bf16(a_l[im], b_h[in], acc[im][in], 0, 0, 0);
            }
    }
    const int qr = (lane >> 4) << 2;
#pragma unroll
    for (int im = 0; im < 2; ++im)
#pragma unroll
        for (int in = 0; in < 2; ++in) {
            int n = n0 + wn * 32 + in * 16 + fr;
            float bv = bias[n];
#pragma unroll
            for (int r = 0; r < 4; ++r) {
                int m = m0 + wm * 32 + im * 16 + qr + r;
                out[(size_t)m * EMBD + n] = acc[im][in][r] + bv;
            }
        }
}

extern "C" void kernel_launch(void* const* d_in, const int* in_sizes, int n_in,
                              void* d_out, int out_size, void* d_ws, size_t ws_size,
                              hipStream_t stream)
{
    const float* x    = (const float*)d_in[0];
    const float* vec  = (const float*)d_in[1];
    const float* Wqkv = (const float*)d_in[2];
    const float* bqkv = (const float*)d_in[3];
    const float* Wb   = (const float*)d_in[4];
    const float* bb   = (const float*)d_in[5];
    const float* Wout = (const float*)d_in[6];
    const float* bout = (const float*)d_in[7];
    float* out = (float*)d_out;

    char* ws = (char*)d_ws;
    u16*   qkvb   = (u16*)(ws);                     //  6,291,456
    u16*   Vt     = (u16*)(ws + 6291456);           //  2,097,152
    float* zpart  = (float*)(ws + 8388608);         //    524,288 (8*8*2048*4)
    float* partsP = (float*)(ws + 8912896);         // 33,554,432
    float* partsB = (float*)(ws + 42467328);        // 33,554,432
    u16*   yh     = (u16*)(ws + 76021760);          //  2,097,152
    u16*   yl     = (u16*)(ws + 78118912);          //  2,097,152
    u16*   xh     = (u16*)(ws + 80216064);          //  2,097,152
    u16*   xl     = (u16*)(ws + 82313216);          //  2,097,152
    u16*   wth    = (u16*)(ws + 84410368);          //  1,572,864
    u16*   wtl    = (u16*)(ws + 85983232);          //  1,572,864
    u16*   woth   = (u16*)(ws + 87556096);          //    524,288
    u16*   wotl   = (u16*)(ws + 88080384);          //    524,288
    // total: 88,604,672 B

    prep<<<1280, 256, 0, stream>>>(x, xh, xl, Wqkv, wth, wtl, Wout, woth, wotl);
    gemm_qkv_mfma<<<dim3(24, 32), 256, 0, stream>>>(xh, xl, wth, wtl, bqkv, qkvb, Vt);
    bias_v<<<64 * KSPLIT, 512, 0, stream>>>(Vt, vec, Wb, bb, partsB);
    attn_pv<<<64 * KSPLIT, 512, 0, stream>>>(qkvb, Vt, zpart, partsP);
    reduce_y2<<<1024, 256, 0, stream>>>(partsP, partsB, zpart, yh, yl);
    gemm_out_mfma<<<dim3(8, 32), 256, 0, stream>>>(yh, yl, woth, wotl, bout, out);
}

// Round 10
// 242.897 us; speedup vs baseline: 1.0505x; 1.0215x over previous
//
#include <hip/hip_runtime.h>
#include <hip/hip_bf16.h>
#include <math.h>

#define NT 2048
#define EMBD 512
#define NH 8
#define QKV_LD 1536
#define KSPLIT 8

typedef unsigned short u16;
typedef __attribute__((ext_vector_type(8))) short short8;
typedef __attribute__((ext_vector_type(4))) float v4f;

static __device__ __forceinline__ float bf2f(unsigned int u) {
    union { unsigned int i; float f; } c; c.i = u << 16; return c.f;
}
static __device__ __forceinline__ unsigned int f2bf(float x) {   // RNE
    union { float f; unsigned int u; } c; c.f = x;
    return (c.u + 0x7fffu + ((c.u >> 16) & 1u)) >> 16;
}
// HW packed f32->bf16 (RNE, bit-identical to f2bf pair) — one inst per pair
static __device__ __forceinline__ unsigned int cvtpk(float lo, float hi) {
    unsigned int r;
    asm("v_cvt_pk_bf16_f32 %0, %1, %2" : "=v"(r) : "v"(lo), "v"(hi));
    return r;
}

// ------- prep: split x (hi/lo) + split+transpose Wqkv and Wout --------------
__global__ __launch_bounds__(256) void prep(const float* __restrict__ x,
    u16* __restrict__ xh, u16* __restrict__ xl,
    const float* __restrict__ Wqkv, u16* __restrict__ wth, u16* __restrict__ wtl,
    const float* __restrict__ Wout, u16* __restrict__ woth, u16* __restrict__ wotl)
{
    __shared__ float tile[64][65];
    int b = blockIdx.x;
    const int t = threadIdx.x;
    if (b < 1024) {                       // ---- split_x region
        int i = (b * 256 + t) << 2;
        float4 v = *(const float4*)(x + i);
        float f[4] = {v.x, v.y, v.z, v.w};
        unsigned int hi[4], lo[4];
#pragma unroll
        for (int j = 0; j < 4; ++j) {
            hi[j] = f2bf(f[j]);
            lo[j] = f2bf(f[j] - bf2f(hi[j]));
        }
        uint2 wh; wh.x = hi[0] | (hi[1] << 16); wh.y = hi[2] | (hi[3] << 16);
        uint2 wl; wl.x = lo[0] | (lo[1] << 16); wl.y = lo[2] | (lo[3] << 16);
        *(uint2*)(xh + i) = wh;
        *(uint2*)(xl + i) = wl;
        return;
    }
    b -= 1024;                            // ---- split_wt regions
    const float* W; u16* th; u16* tl; int ld, bx, by;
    if (b < 192) { W = Wqkv; th = wth;  tl = wtl;  ld = QKV_LD; bx = b % 24; by = b / 24; }
    else { b -= 192; W = Wout; th = woth; tl = wotl; ld = EMBD; bx = b & 7; by = b >> 3; }
    const int n0 = bx << 6, k0 = by << 6;
    const int r = t >> 2, c4 = (t & 3) << 4;
#pragma unroll
    for (int j = 0; j < 4; ++j)
        *(float4*)&tile[r][c4 + (j << 2)] =
            *(const float4*)(W + (size_t)(k0 + r) * ld + n0 + c4 + (j << 2));
    __syncthreads();
    const int n_l = t >> 2;
    u16 vh[16], vl[16];
#pragma unroll
    for (int j = 0; j < 16; ++j) {
        float f = tile[c4 + j][n_l];
        unsigned int h = f2bf(f);
        vh[j] = (u16)h;
        vl[j] = (u16)f2bf(f - bf2f(h));
    }
    u16* dh = th + (size_t)(n0 + n_l) * EMBD + k0 + c4;
    u16* dl = tl + (size_t)(n0 + n_l) * EMBD + k0 + c4;
    *(uint4*)dh       = *(uint4*)&vh[0];
    *(uint4*)(dh + 8) = *(uint4*)&vh[8];
    *(uint4*)dl       = *(uint4*)&vl[0];
    *(uint4*)(dl + 8) = *(uint4*)&vl[8];
}

// ------- qkv = x @ Wqkv + b via split-precision bf16 MFMA (R7 verbatim) -----
__global__ __launch_bounds__(256) void gemm_qkv_mfma(const u16* __restrict__ xh,
    const u16* __restrict__ xl, const u16* __restrict__ wth,
    const u16* __restrict__ wtl, const float* __restrict__ bias,
    u16* __restrict__ qkvb)
{
    const int n0 = blockIdx.x << 6, m0 = blockIdx.y << 6;
    const int w = threadIdx.x >> 6, lane = threadIdx.x & 63;
    const int wm = w >> 1, wn = w & 1;
    const int fr = lane & 15, kd = (lane >> 4) << 3;

    const u16* ah0 = xh + (size_t)(m0 + wm * 32 + fr) * EMBD + kd;
    const u16* al0 = xl + (size_t)(m0 + wm * 32 + fr) * EMBD + kd;
    const u16* bh0 = wth + (size_t)(n0 + wn * 32 + fr) * EMBD + kd;
    const u16* bl0 = wtl + (size_t)(n0 + wn * 32 + fr) * EMBD + kd;

    v4f acc[2][2] = {};
    for (int kc = 0; kc < EMBD; kc += 32) {
        short8 a_h[2], a_l[2], b_h[2], b_l[2];
#pragma unroll
        for (int im = 0; im < 2; ++im) {
            a_h[im] = *(const short8*)(ah0 + (size_t)im * 16 * EMBD + kc);
            a_l[im] = *(const short8*)(al0 + (size_t)im * 16 * EMBD + kc);
        }
#pragma unroll
        for (int in = 0; in < 2; ++in) {
            b_h[in] = *(const short8*)(bh0 + (size_t)in * 16 * EMBD + kc);
            b_l[in] = *(const short8*)(bl0 + (size_t)in * 16 * EMBD + kc);
        }
#pragma unroll
        for (int im = 0; im < 2; ++im)
#pragma unroll
            for (int in = 0; in < 2; ++in) {
                acc[im][in] = __builtin_amdgcn_mfma_f32_16x16x32_bf16(a_h[im], b_h[in], acc[im][in], 0, 0, 0);
                acc[im][in] = __builtin_amdgcn_mfma_f32_16x16x32_bf16(a_h[im], b_l[in], acc[im][in], 0, 0, 0);
                acc[im][in] = __builtin_amdgcn_mfma_f32_16x16x32_bf16(a_l[im], b_h[in], acc[im][in], 0, 0, 0);
            }
    }
    const int qr = (lane >> 4) << 2;
#pragma unroll
    for (int im = 0; im < 2; ++im)
#pragma unroll
        for (int in = 0; in < 2; ++in) {
            int n = n0 + wn * 32 + in * 16 + fr;
            float bv = bias[n];
#pragma unroll
            for (int r = 0; r < 4; ++r) {
                int m = m0 + wm * 32 + im * 16 + qr + r;
                qkvb[(size_t)m * QKV_LD + n] = (u16)f2bf(acc[im][in][r] + bv);
            }
        }
}

// ------- V transpose: Vt[h][t][k] <- qkv[k][h*192+128+t] (R7 verbatim) -----
__global__ __launch_bounds__(256) void transpose_v(const u16* __restrict__ qkvb,
                                                   u16* __restrict__ Vt)
{
    __shared__ u16 tile[64][72];
    const int h = blockIdx.y, k0 = blockIdx.x << 6;
    const int t = threadIdx.x;
    {
        int r = t >> 2, cg = (t & 3) << 4;
        const u16* src = qkvb + (size_t)(k0 + r) * QKV_LD + h * 192 + 128 + cg;
        *(uint4*)&tile[r][cg]     = *(const uint4*)src;
        *(uint4*)&tile[r][cg + 8] = *(const uint4*)(src + 8);
    }
    __syncthreads();
    {
        int c = t >> 2, kg = (t & 3) << 4;
        u16 tmp[16];
#pragma unroll
        for (int j = 0; j < 16; ++j) tmp[j] = tile[kg + j][c];
        u16* dst = Vt + ((size_t)h * 64 + c) * NT + k0 + kg;
        *(uint4*)dst       = *(uint4*)&tmp[0];
        *(uint4*)(dst + 8) = *(uint4*)&tmp[8];
    }
}

// ==== attn_pv: QK^T -> exp/z -> P@V (split-K=8), R7 verbatim ================
__global__ __launch_bounds__(512, 2) void attn_pv(
    const u16* __restrict__ qkvb, const u16* __restrict__ Vt,
    float* __restrict__ zpart, float* __restrict__ partsP)
{
    __shared__ u16 tile[8 * 2056];

    const int bid = blockIdx.x;
    const int zsp = bid & 7;
    const int qt  = bid >> 3;
    const int q0 = qt << 5;
    const int kbase = zsp << 8;

    const int t = threadIdx.x;
    const int w = t >> 6;              // wave = head
    const int lane = t & 63;
    const int fr = lane & 15;
    const int hi4 = lane >> 4;
    const int kd = hi4 << 3;
    const int qr = hi4 << 2;

    short8 aq[2][2];
#pragma unroll
    for (int mb = 0; mb < 2; ++mb)
#pragma unroll
        for (int kk = 0; kk < 2; ++kk)
            aq[mb][kk] = *(const short8*)(qkvb +
                (size_t)(q0 + mb * 16 + fr) * QKV_LD + w * 192 + kk * 32 + kd);

    v4f accP[2][4] = {};
    float zacc[2][4] = {};

    const u16* vsrc = Vt + (size_t)(w * 64 + fr) * NT + kd;
    const u16* ksrc = qkvb + (size_t)fr * QKV_LD + w * 192 + 64 + kd;

#define LOADCH(VB, BK, KC)                                                     \
    _Pragma("unroll")                                                          \
    for (int nt = 0; nt < 4; ++nt)                                             \
        _Pragma("unroll")                                                      \
        for (int kk = 0; kk < 2; ++kk) {                                       \
            VB[nt][kk] = *(const short8*)(vsrc + (size_t)nt * 16 * NT +        \
                                          (KC) + kk * 32);                     \
            BK[nt][kk] = *(const short8*)(ksrc + (size_t)((KC) + nt * 16) *    \
                                          QKV_LD + kk * 32);                   \
        }

#define COMPUTECH(VB, BK)                                                      \
    {                                                                          \
        v4f sacc[2][4] = {};                                                   \
        _Pragma("unroll")                                                      \
        for (int mb = 0; mb < 2; ++mb)                                         \
            _Pragma("unroll")                                                  \
            for (int nt = 0; nt < 4; ++nt) {                                   \
                sacc[mb][nt] = __builtin_amdgcn_mfma_f32_16x16x32_bf16(        \
                    aq[mb][0], BK[nt][0], sacc[mb][nt], 0, 0, 0);              \
                sacc[mb][nt] = __builtin_amdgcn_mfma_f32_16x16x32_bf16(        \
                    aq[mb][1], BK[nt][1], sacc[mb][nt], 0, 0, 0);              \
            }                                                                  \
        unsigned int pk[2][4][2];                                              \
        _Pragma("unroll")                                                      \
        for (int mb = 0; mb < 2; ++mb)                                         \
            _Pragma("unroll")                                                  \
            for (int nt = 0; nt < 4; ++nt)                                     \
                _Pragma("unroll")                                              \
                for (int r2 = 0; r2 < 2; ++r2) {                               \
                    float e0 = __expf(sacc[mb][nt][2 * r2] * 0.125f);          \
                    float e1 = __expf(sacc[mb][nt][2 * r2 + 1] * 0.125f);      \
                    zacc[mb][2 * r2] += e0;                                    \
                    zacc[mb][2 * r2 + 1] += e1;                                \
                    pk[mb][nt][r2] = cvtpk(e0, e1);                            \
                }                                                              \
        _Pragma("unroll")                                                      \
        for (int mb = 0; mb < 2; ++mb)                                         \
            _Pragma("unroll")                                                  \
            for (int nt = 0; nt < 4; ++nt) {                                   \
                const int kg = (nt << 1) + (fr >> 3);                          \
                _Pragma("unroll")                                              \
                for (int r = 0; r < 4; ++r) {                                  \
                    const int q = mb * 16 + qr + r;                            \
                    tile[w * 2056 + q * 64 + ((kg ^ (q & 7)) << 3) +           \
                         (fr & 7)] =                                           \
                        (u16)(pk[mb][nt][r >> 1] >> ((r & 1) << 4));           \
                }                                                              \
            }                                                                  \
        _Pragma("unroll")                                                      \
        for (int mb = 0; mb < 2; ++mb) {                                       \
            const int q = mb * 16 + fr;                                        \
            _Pragma("unroll")                                                  \
            for (int kk = 0; kk < 2; ++kk) {                                   \
                short8 ap = *(const short8*)&tile[w * 2056 + q * 64 +          \
                    (((kk * 4 + hi4) ^ (q & 7)) << 3)];                        \
                _Pragma("unroll")                                              \
                for (int nt = 0; nt < 4; ++nt)                                 \
                    accP[mb][nt] = __builtin_amdgcn_mfma_f32_16x16x32_bf16(    \
                        ap, VB[nt][kk], accP[mb][nt], 0, 0, 0);                \
            }                                                                  \
        }                                                                      \
    }

    short8 v0[4][2], b0[4][2], v1[4][2], b1[4][2];
    LOADCH(v0, b0, kbase)
#pragma unroll
    for (int cc = 0; cc < 2; ++cc) {
        LOADCH(v1, b1, kbase + ((2 * cc + 1) << 6))
        COMPUTECH(v0, b0)
        if (cc < 1) { LOADCH(v0, b0, kbase + ((2 * cc + 2) << 6)) }
        COMPUTECH(v1, b1)
    }
#undef LOADCH
#undef COMPUTECH

    // epilogue: z reduce + partial writes
#pragma unroll
    for (int off = 1; off < 16; off <<= 1)
#pragma unroll
        for (int mb = 0; mb < 2; ++mb)
#pragma unroll
            for (int r = 0; r < 4; ++r)
                zacc[mb][r] += __shfl_xor(zacc[mb][r], off);
    if (fr == 0) {
#pragma unroll
        for (int mb = 0; mb < 2; ++mb)
#pragma unroll
            for (int r = 0; r < 4; ++r)
                zpart[((size_t)zsp * 8 + w) * NT + q0 + mb * 16 + qr + r] = zacc[mb][r];
    }
    float* pP = partsP + (size_t)zsp * NT * EMBD;
#pragma unroll
    for (int mb = 0; mb < 2; ++mb)
#pragma unroll
        for (int nt = 0; nt < 4; ++nt)
#pragma unroll
            for (int r = 0; r < 4; ++r)
                pP[(size_t)(q0 + mb * 16 + qr + r) * EMBD +
                   (w << 6) + (nt << 4) + fr] = accP[mb][nt][r];
}

// ==== bias_v: angles -> sincos -> MFMA head-proj -> bias@V (split-K=8) ======
// R7 geometry + DE-CONFOUNDED barrier reduction (R9 retried without gathers):
//  - flds/vql stay LDS-staged (coalesced; R9's global vq gathers caused the
//    regression, FETCH 1.2->4.5MB).
//  - phase A wave-private: wave w computes its own 256 angles into angw strip
//    (idx = lane + 64*jj -> lane-contiguous LDS writes, coalesced vk reads);
//    B reads only its own strip -> no A<->B barrier.
//  - bias tile double-buffered -> single B->C barrier per chunk (5 barriers
//    total vs R7's 9). Hazard audit: B(c) writes tile[c&1] after barrier(c-1);
//    all waves' C(c-2) precede barrier(c-1) in program order.
// Identical op sequences on identical inputs -> partsB bit-identical to R7.
__global__ __launch_bounds__(512, 4) void bias_v(
    const u16* __restrict__ Vt, const float* __restrict__ vec,
    const float* __restrict__ Wb, const float* __restrict__ bb,
    float* __restrict__ partsB)
{
    __shared__ float flds[32];
    __shared__ float vql[96];
    __shared__ float angw[8 * 260];       // per-wave 256 angles (+4 pad)
    __shared__ u16 tile[2][8 * 2056];     // double-buffered bias tile

    const int bid = blockIdx.x;
    const int zsp = bid & 7;
    const int qt  = bid >> 3;
    const int q0 = qt << 5;
    const int kbase = zsp << 8;

    const int t = threadIdx.x;
    const int w = t >> 6;              // wave = head
    const int lane = t & 63;
    const int fr = lane & 15;
    const int hi4 = lane >> 4;
    const int kd = hi4 << 3;
    const int qr = hi4 << 2;

    if (t < 32) flds[t] = __fdiv_rn(__fdiv_rn((float)t, 31.0f), 0.1f);
    else if (t < 128) vql[t - 32] = vec[q0 * 3 + (t - 32)];

    short8 BS, BC;
#pragma unroll
    for (int j = 0; j < 8; ++j) {
        float ws = (fr < 8) ? Wb[(kd + j) * 8 + fr] : 0.0f;
        float wc = (fr < 8) ? Wb[(32 + kd + j) * 8 + fr] : 0.0f;
        BS[j] = (short)f2bf(ws);
        BC[j] = (short)f2bf(wc);
    }
    const float bbv = (fr < 8) ? bb[fr] : 0.0f;

    v4f accB[2][4] = {};

    __syncthreads();   // prologue: flds/vql visible to all waves

    for (int c = 0; c < 4; ++c) {
        const int kc = kbase + (c << 6);
        u16* tp = tile[c & 1];
        // ---- phase A (wave-private): 4 angles/lane, frozen numerics
#pragma unroll
        for (int jj = 0; jj < 4; ++jj) {
            const int idx = lane + (jj << 6);       // 0..255, lane-contiguous
            const int gi = idx >> 4;
            const int g = w + (gi << 3);
            const int q = g >> 2;                   // 0..31
            const int kl = ((g & 3) << 4) + (idx & 15);
            const float a0 = vql[q * 3], a1 = vql[q * 3 + 1], a2 = vql[q * 3 + 2];
            const float* vk = vec + (size_t)(kc + kl) * 3;
            float c0 = vk[0], c1 = vk[1], c2 = vk[2];
            float dot = __fadd_rn(__fadd_rn(__fmul_rn(a0, c0), __fmul_rn(a1, c1)),
                                  __fmul_rn(a2, c2));
            float dotc = fminf(fmaxf(dot, 0.0f), 1.0f);
            angw[w * 260 + idx] = __fdiv_rn(acosf(dotc), 0.001f);
        }
        // (no barrier: wave w reads only angw[w*260..] in phase B)
        // ---- phase B: sincos features -> MFMA projection -> bias tile
#pragma unroll
        for (int gi = 0; gi < 16; ++gi) {
            const int g = w + (gi << 3);
            const int q = g >> 2;
            const int ksub = (g & 3) << 4;
            const float av = angw[w * 260 + (gi << 4) + fr];
            float sv[8], cv[8];
#pragma unroll
            for (int j = 0; j < 8; ++j) {
                float ph = __fmul_rn(flds[kd + j], av);
                float rv = ph * 0.15915494309189535f;
                float rf = rv - floorf(rv);
                sv[j] = __builtin_amdgcn_sinf(rf);
                cv[j] = __builtin_amdgcn_cosf(rf);
            }
            union { uint4 u; short8 v; } As, Ac;
            As.u.x = cvtpk(sv[0], sv[1]); As.u.y = cvtpk(sv[2], sv[3]);
            As.u.z = cvtpk(sv[4], sv[5]); As.u.w = cvtpk(sv[6], sv[7]);
            Ac.u.x = cvtpk(cv[0], cv[1]); Ac.u.y = cvtpk(cv[2], cv[3]);
            Ac.u.z = cvtpk(cv[4], cv[5]); Ac.u.w = cvtpk(cv[6], cv[7]);
            v4f cb = {};
            cb = __builtin_amdgcn_mfma_f32_16x16x32_bf16(As.v, BS, cb, 0, 0, 0);
            cb = __builtin_amdgcn_mfma_f32_16x16x32_bf16(Ac.v, BC, cb, 0, 0, 0);
            if (fr < 8) {
                const int kg = (ksub + qr) >> 3;
                uint2 wv;
                wv.x = cvtpk(cb[0] + bbv, cb[1] + bbv);
                wv.y = cvtpk(cb[2] + bbv, cb[3] + bbv);
                *(uint2*)&tp[fr * 2056 + q * 64 + ((kg ^ (q & 7)) << 3) + (qr & 7)] = wv;
            }
        }
        __syncthreads();   // the one real cross-wave handoff (B -> C)
        // ---- phase C: accB += bias@V (accum order verbatim R7)
#pragma unroll
        for (int kk = 0; kk < 2; ++kk) {
            const int q0l = 0 * 16 + fr, q1l = 1 * 16 + fr;
            short8 ab0 = *(const short8*)&tp[w * 2056 + q0l * 64 +
                (((kk * 4 + hi4) ^ (q0l & 7)) << 3)];
            short8 ab1 = *(const short8*)&tp[w * 2056 + q1l * 64 +
                (((kk * 4 + hi4) ^ (q1l & 7)) << 3)];
#pragma unroll
            for (int nt = 0; nt < 4; ++nt) {
                short8 vbx = *(const short8*)(Vt +
                    (size_t)(w * 64 + nt * 16 + fr) * NT + kc + kk * 32 + kd);
                accB[0][nt] = __builtin_amdgcn_mfma_f32_16x16x32_bf16(ab0, vbx, accB[0][nt], 0, 0, 0);
                accB[1][nt] = __builtin_amdgcn_mfma_f32_16x16x32_bf16(ab1, vbx, accB[1][nt], 0, 0, 0);
            }
        }
        // C(c) vs B(c+2) reuse of tile[c&1] is ordered by barrier(c+1).
    }
    float* pB = partsB + (size_t)zsp * NT * EMBD;
#pragma unroll
    for (int mb = 0; mb < 2; ++mb)
#pragma unroll
        for (int nt = 0; nt < 4; ++nt)
#pragma unroll
            for (int r = 0; r < 4; ++r)
                pB[(size_t)(q0 + mb * 16 + qr + r) * EMBD +
                   (w << 6) + (nt << 4) + fr] = accB[mb][nt][r];
}

// ------- reduce 8 partials: y = sumP/sumZ + sumB -> bf16 hi/lo --------------
__global__ __launch_bounds__(256) void reduce_y2(const float* __restrict__ partsP,
    const float* __restrict__ partsB, const float* __restrict__ zpart,
    u16* __restrict__ yh, u16* __restrict__ yl)
{
    const int MN = NT * EMBD;
    int i = (blockIdx.x * 256 + threadIdx.x) << 2;
    const int q = i >> 9;
    const int h = (i & 511) >> 6;
    float zs = 0.0f;
#pragma unroll
    for (int z = 0; z < KSPLIT; ++z) zs += zpart[((size_t)z * 8 + h) * NT + q];
    float4 aP = *(const float4*)(partsP + i);
    float4 aB = *(const float4*)(partsB + i);
#pragma unroll
    for (int z = 1; z < KSPLIT; ++z) {
        float4 p = *(const float4*)(partsP + (size_t)z * MN + i);
        float4 b = *(const float4*)(partsB + (size_t)z * MN + i);
        aP.x += p.x; aP.y += p.y; aP.z += p.z; aP.w += p.w;
        aB.x += b.x; aB.y += b.y; aB.z += b.z; aB.w += b.w;
    }
    const float iz = 1.0f / zs;
    float f[4] = {aP.x * iz + aB.x, aP.y * iz + aB.y,
                  aP.z * iz + aB.z, aP.w * iz + aB.w};
    unsigned int hi[4], lo[4];
#pragma unroll
    for (int j = 0; j < 4; ++j) {
        hi[j] = f2bf(f[j]);
        lo[j] = f2bf(f[j] - bf2f(hi[j]));
    }
    uint2 wh; wh.x = hi[0] | (hi[1] << 16); wh.y = hi[2] | (hi[3] << 16);
    uint2 wl; wl.x = lo[0] | (lo[1] << 16); wl.y = lo[2] | (lo[3] << 16);
    *(uint2*)(yh + i) = wh;
    *(uint2*)(yl + i) = wl;
}

// ------- out = y @ Wout + bout via split-precision bf16 MFMA ----------------
__global__ __launch_bounds__(256) void gemm_out_mfma(const u16* __restrict__ yh,
    const u16* __restrict__ yl, const u16* __restrict__ wh,
    const u16* __restrict__ wl, const float* __restrict__ bias,
    float* __restrict__ out)
{
    const int n0 = blockIdx.x << 6, m0 = blockIdx.y << 6;
    const int w = threadIdx.x >> 6, lane = threadIdx.x & 63;
    const int wm = w >> 1, wn = w & 1;
    const int fr = lane & 15, kd = (lane >> 4) << 3;

    const u16* ah0 = yh + (size_t)(m0 + wm * 32 + fr) * EMBD + kd;
    const u16* al0 = yl + (size_t)(m0 + wm * 32 + fr) * EMBD + kd;
    const u16* bh0 = wh + (size_t)(n0 + wn * 32 + fr) * EMBD + kd;
    const u16* bl0 = wl + (size_t)(n0 + wn * 32 + fr) * EMBD + kd;

    v4f acc[2][2] = {};
    for (int kc = 0; kc < EMBD; kc += 32) {
        short8 a_h[2], a_l[2], b_h[2], b_l[2];
#pragma unroll
        for (int im = 0; im < 2; ++im) {
            a_h[im] = *(const short8*)(ah0 + (size_t)im * 16 * EMBD + kc);
            a_l[im] = *(const short8*)(al0 + (size_t)im * 16 * EMBD + kc);
        }
#pragma unroll
        for (int in = 0; in < 2; ++in) {
            b_h[in] = *(const short8*)(bh0 + (size_t)in * 16 * EMBD + kc);
            b_l[in] = *(const short8*)(bl0 + (size_t)in * 16 * EMBD + kc);
        }
#pragma unroll
        for (int im = 0; im < 2; ++im)
#pragma unroll
            for (int in = 0; in < 2; ++in) {
                acc[im][in] = __builtin_amdgcn_mfma_f32_16x16x32_bf16(a_h[im], b_h[in], acc[im][in], 0, 0, 0);
                acc[im][in] = __builtin_amdgcn_mfma_f32_16x16x32_bf16(a_h[im], b_l[in], acc[im][in], 0, 0, 0);
                acc[im][in] = __builtin_amdgcn_mfma_f32_16x16x32_bf16(a_l[im], b_h[in], acc[im][in], 0, 0, 0);
            }
    }
    const int qr = (lane >> 4) << 2;
#pragma unroll
    for (int im = 0; im < 2; ++im)
#pragma unroll
        for (int in = 0; in < 2; ++in) {
            int n = n0 + wn * 32 + in * 16 + fr;
            float bv = bias[n];
#pragma unroll
            for (int r = 0; r < 4; ++r) {
                int m = m0 + wm * 32 + im * 16 + qr + r;
                out[(size_t)m * EMBD + n] = acc[im][in][r] + bv;
            }
        }
}

extern "C" void kernel_launch(void* const* d_in, const int* in_sizes, int n_in,
                              void* d_out, int out_size, void* d_ws, size_t ws_size,
                              hipStream_t stream)
{
    const float* x    = (const float*)d_in[0];
    const float* vec  = (const float*)d_in[1];
    const float* Wqkv = (const float*)d_in[2];
    const float* bqkv = (const float*)d_in[3];
    const float* Wb   = (const float*)d_in[4];
    const float* bb   = (const float*)d_in[5];
    const float* Wout = (const float*)d_in[6];
    const float* bout = (const float*)d_in[7];
    float* out = (float*)d_out;

    char* ws = (char*)d_ws;
    u16*   qkvb   = (u16*)(ws);                     //  6,291,456
    u16*   Vt     = (u16*)(ws + 6291456);           //  2,097,152
    float* zpart  = (float*)(ws + 8388608);         //    524,288 (8*8*2048*4)
    float* partsP = (float*)(ws + 8912896);         // 33,554,432
    float* partsB = (float*)(ws + 42467328);        // 33,554,432
    u16*   yh     = (u16*)(ws + 76021760);          //  2,097,152
    u16*   yl     = (u16*)(ws + 78118912);          //  2,097,152
    u16*   xh     = (u16*)(ws + 80216064);          //  2,097,152
    u16*   xl     = (u16*)(ws + 82313216);          //  2,097,152
    u16*   wth    = (u16*)(ws + 84410368);          //  1,572,864
    u16*   wtl    = (u16*)(ws + 85983232);          //  1,572,864
    u16*   woth   = (u16*)(ws + 87556096);          //    524,288
    u16*   wotl   = (u16*)(ws + 88080384);          //    524,288
    // total: 88,604,672 B

    prep<<<1280, 256, 0, stream>>>(x, xh, xl, Wqkv, wth, wtl, Wout, woth, wotl);
    gemm_qkv_mfma<<<dim3(24, 32), 256, 0, stream>>>(xh, xl, wth, wtl, bqkv, qkvb);
    transpose_v<<<dim3(32, 8), 256, 0, stream>>>(qkvb, Vt);
    bias_v<<<64 * KSPLIT, 512, 0, stream>>>(Vt, vec, Wb, bb, partsB);
    attn_pv<<<64 * KSPLIT, 512, 0, stream>>>(qkvb, Vt, zpart, partsP);
    reduce_y2<<<1024, 256, 0, stream>>>(partsP, partsB, zpart, yh, yl);
    gemm_out_mfma<<<dim3(8, 32), 256, 0, stream>>>(yh, yl, woth, wotl, bout, out);
}

// Round 11
// 242.598 us; speedup vs baseline: 1.0518x; 1.0012x over previous
//
#include <hip/hip_runtime.h>
#include <hip/hip_bf16.h>
#include <math.h>

#define NT 2048
#define EMBD 512
#define NH 8
#define QKV_LD 1536
#define KSPLIT 8

typedef unsigned short u16;
typedef __attribute__((ext_vector_type(8))) short short8;
typedef __attribute__((ext_vector_type(4))) float v4f;

static __device__ __forceinline__ float bf2f(unsigned int u) {
    union { unsigned int i; float f; } c; c.i = u << 16; return c.f;
}
static __device__ __forceinline__ unsigned int f2bf(float x) {   // RNE
    union { float f; unsigned int u; } c; c.f = x;
    return (c.u + 0x7fffu + ((c.u >> 16) & 1u)) >> 16;
}
// HW packed f32->bf16 (RNE, bit-identical to f2bf pair) — one inst per pair
static __device__ __forceinline__ unsigned int cvtpk(float lo, float hi) {
    unsigned int r;
    asm("v_cvt_pk_bf16_f32 %0, %1, %2" : "=v"(r) : "v"(lo), "v"(hi));
    return r;
}

// ------- prep: split x (hi/lo) + split+transpose Wqkv and Wout --------------
__global__ __launch_bounds__(256) void prep(const float* __restrict__ x,
    u16* __restrict__ xh, u16* __restrict__ xl,
    const float* __restrict__ Wqkv, u16* __restrict__ wth, u16* __restrict__ wtl,
    const float* __restrict__ Wout, u16* __restrict__ woth, u16* __restrict__ wotl)
{
    __shared__ float tile[64][65];
    int b = blockIdx.x;
    const int t = threadIdx.x;
    if (b < 1024) {                       // ---- split_x region
        int i = (b * 256 + t) << 2;
        float4 v = *(const float4*)(x + i);
        float f[4] = {v.x, v.y, v.z, v.w};
        unsigned int hi[4], lo[4];
#pragma unroll
        for (int j = 0; j < 4; ++j) {
            hi[j] = f2bf(f[j]);
            lo[j] = f2bf(f[j] - bf2f(hi[j]));
        }
        uint2 wh; wh.x = hi[0] | (hi[1] << 16); wh.y = hi[2] | (hi[3] << 16);
        uint2 wl; wl.x = lo[0] | (lo[1] << 16); wl.y = lo[2] | (lo[3] << 16);
        *(uint2*)(xh + i) = wh;
        *(uint2*)(xl + i) = wl;
        return;
    }
    b -= 1024;                            // ---- split_wt regions
    const float* W; u16* th; u16* tl; int ld, bx, by;
    if (b < 192) { W = Wqkv; th = wth;  tl = wtl;  ld = QKV_LD; bx = b % 24; by = b / 24; }
    else { b -= 192; W = Wout; th = woth; tl = wotl; ld = EMBD; bx = b & 7; by = b >> 3; }
    const int n0 = bx << 6, k0 = by << 6;
    const int r = t >> 2, c4 = (t & 3) << 4;
#pragma unroll
    for (int j = 0; j < 4; ++j)
        *(float4*)&tile[r][c4 + (j << 2)] =
            *(const float4*)(W + (size_t)(k0 + r) * ld + n0 + c4 + (j << 2));
    __syncthreads();
    const int n_l = t >> 2;
    u16 vh[16], vl[16];
#pragma unroll
    for (int j = 0; j < 16; ++j) {
        float f = tile[c4 + j][n_l];
        unsigned int h = f2bf(f);
        vh[j] = (u16)h;
        vl[j] = (u16)f2bf(f - bf2f(h));
    }
    u16* dh = th + (size_t)(n0 + n_l) * EMBD + k0 + c4;
    u16* dl = tl + (size_t)(n0 + n_l) * EMBD + k0 + c4;
    *(uint4*)dh       = *(uint4*)&vh[0];
    *(uint4*)(dh + 8) = *(uint4*)&vh[8];
    *(uint4*)dl       = *(uint4*)&vl[0];
    *(uint4*)(dl + 8) = *(uint4*)&vl[8];
}

// ------- qkv = x @ Wqkv + b via split-precision bf16 MFMA (R7 verbatim) -----
__global__ __launch_bounds__(256) void gemm_qkv_mfma(const u16* __restrict__ xh,
    const u16* __restrict__ xl, const u16* __restrict__ wth,
    const u16* __restrict__ wtl, const float* __restrict__ bias,
    u16* __restrict__ qkvb)
{
    const int n0 = blockIdx.x << 6, m0 = blockIdx.y << 6;
    const int w = threadIdx.x >> 6, lane = threadIdx.x & 63;
    const int wm = w >> 1, wn = w & 1;
    const int fr = lane & 15, kd = (lane >> 4) << 3;

    const u16* ah0 = xh + (size_t)(m0 + wm * 32 + fr) * EMBD + kd;
    const u16* al0 = xl + (size_t)(m0 + wm * 32 + fr) * EMBD + kd;
    const u16* bh0 = wth + (size_t)(n0 + wn * 32 + fr) * EMBD + kd;
    const u16* bl0 = wtl + (size_t)(n0 + wn * 32 + fr) * EMBD + kd;

    v4f acc[2][2] = {};
    for (int kc = 0; kc < EMBD; kc += 32) {
        short8 a_h[2], a_l[2], b_h[2], b_l[2];
#pragma unroll
        for (int im = 0; im < 2; ++im) {
            a_h[im] = *(const short8*)(ah0 + (size_t)im * 16 * EMBD + kc);
            a_l[im] = *(const short8*)(al0 + (size_t)im * 16 * EMBD + kc);
        }
#pragma unroll
        for (int in = 0; in < 2; ++in) {
            b_h[in] = *(const short8*)(bh0 + (size_t)in * 16 * EMBD + kc);
            b_l[in] = *(const short8*)(bl0 + (size_t)in * 16 * EMBD + kc);
        }
#pragma unroll
        for (int im = 0; im < 2; ++im)
#pragma unroll
            for (int in = 0; in < 2; ++in) {
                acc[im][in] = __builtin_amdgcn_mfma_f32_16x16x32_bf16(a_h[im], b_h[in], acc[im][in], 0, 0, 0);
                acc[im][in] = __builtin_amdgcn_mfma_f32_16x16x32_bf16(a_h[im], b_l[in], acc[im][in], 0, 0, 0);
                acc[im][in] = __builtin_amdgcn_mfma_f32_16x16x32_bf16(a_l[im], b_h[in], acc[im][in], 0, 0, 0);
            }
    }
    const int qr = (lane >> 4) << 2;
#pragma unroll
    for (int im = 0; im < 2; ++im)
#pragma unroll
        for (int in = 0; in < 2; ++in) {
            int n = n0 + wn * 32 + in * 16 + fr;
            float bv = bias[n];
#pragma unroll
            for (int r = 0; r < 4; ++r) {
                int m = m0 + wm * 32 + im * 16 + qr + r;
                qkvb[(size_t)m * QKV_LD + n] = (u16)f2bf(acc[im][in][r] + bv);
            }
        }
}

// ------- V transpose: Vt[h][t][k] <- qkv[k][h*192+128+t] (R7 verbatim) -----
__global__ __launch_bounds__(256) void transpose_v(const u16* __restrict__ qkvb,
                                                   u16* __restrict__ Vt)
{
    __shared__ u16 tile[64][72];
    const int h = blockIdx.y, k0 = blockIdx.x << 6;
    const int t = threadIdx.x;
    {
        int r = t >> 2, cg = (t & 3) << 4;
        const u16* src = qkvb + (size_t)(k0 + r) * QKV_LD + h * 192 + 128 + cg;
        *(uint4*)&tile[r][cg]     = *(const uint4*)src;
        *(uint4*)&tile[r][cg + 8] = *(const uint4*)(src + 8);
    }
    __syncthreads();
    {
        int c = t >> 2, kg = (t & 3) << 4;
        u16 tmp[16];
#pragma unroll
        for (int j = 0; j < 16; ++j) tmp[j] = tile[kg + j][c];
        u16* dst = Vt + ((size_t)h * 64 + c) * NT + k0 + kg;
        *(uint4*)dst       = *(uint4*)&tmp[0];
        *(uint4*)(dst + 8) = *(uint4*)&tmp[8];
    }
}

// ==== attn_pv: QK^T -> exp/z -> P@V (split-K=8), R7 verbatim ================
__global__ __launch_bounds__(512, 2) void attn_pv(
    const u16* __restrict__ qkvb, const u16* __restrict__ Vt,
    float* __restrict__ zpart, float* __restrict__ partsP)
{
    __shared__ u16 tile[8 * 2056];

    const int bid = blockIdx.x;
    const int zsp = bid & 7;
    const int qt  = bid >> 3;
    const int q0 = qt << 5;
    const int kbase = zsp << 8;

    const int t = threadIdx.x;
    const int w = t >> 6;              // wave = head
    const int lane = t & 63;
    const int fr = lane & 15;
    const int hi4 = lane >> 4;
    const int kd = hi4 << 3;
    const int qr = hi4 << 2;

    short8 aq[2][2];
#pragma unroll
    for (int mb = 0; mb < 2; ++mb)
#pragma unroll
        for (int kk = 0; kk < 2; ++kk)
            aq[mb][kk] = *(const short8*)(qkvb +
                (size_t)(q0 + mb * 16 + fr) * QKV_LD + w * 192 + kk * 32 + kd);

    v4f accP[2][4] = {};
    float zacc[2][4] = {};

    const u16* vsrc = Vt + (size_t)(w * 64 + fr) * NT + kd;
    const u16* ksrc = qkvb + (size_t)fr * QKV_LD + w * 192 + 64 + kd;

#define LOADCH(VB, BK, KC)                                                     \
    _Pragma("unroll")                                                          \
    for (int nt = 0; nt < 4; ++nt)                                             \
        _Pragma("unroll")                                                      \
        for (int kk = 0; kk < 2; ++kk) {                                       \
            VB[nt][kk] = *(const short8*)(vsrc + (size_t)nt * 16 * NT +        \
                                          (KC) + kk * 32);                     \
            BK[nt][kk] = *(const short8*)(ksrc + (size_t)((KC) + nt * 16) *    \
                                          QKV_LD + kk * 32);                   \
        }

#define COMPUTECH(VB, BK)                                                      \
    {                                                                          \
        v4f sacc[2][4] = {};                                                   \
        _Pragma("unroll")                                                      \
        for (int mb = 0; mb < 2; ++mb)                                         \
            _Pragma("unroll")                                                  \
            for (int nt = 0; nt < 4; ++nt) {                                   \
                sacc[mb][nt] = __builtin_amdgcn_mfma_f32_16x16x32_bf16(        \
                    aq[mb][0], BK[nt][0], sacc[mb][nt], 0, 0, 0);              \
                sacc[mb][nt] = __builtin_amdgcn_mfma_f32_16x16x32_bf16(        \
                    aq[mb][1], BK[nt][1], sacc[mb][nt], 0, 0, 0);              \
            }                                                                  \
        unsigned int pk[2][4][2];                                              \
        _Pragma("unroll")                                                      \
        for (int mb = 0; mb < 2; ++mb)                                         \
            _Pragma("unroll")                                                  \
            for (int nt = 0; nt < 4; ++nt)                                     \
                _Pragma("unroll")                                              \
                for (int r2 = 0; r2 < 2; ++r2) {                               \
                    float e0 = __expf(sacc[mb][nt][2 * r2] * 0.125f);          \
                    float e1 = __expf(sacc[mb][nt][2 * r2 + 1] * 0.125f);      \
                    zacc[mb][2 * r2] += e0;                                    \
                    zacc[mb][2 * r2 + 1] += e1;                                \
                    pk[mb][nt][r2] = cvtpk(e0, e1);                            \
                }                                                              \
        _Pragma("unroll")                                                      \
        for (int mb = 0; mb < 2; ++mb)                                         \
            _Pragma("unroll")                                                  \
            for (int nt = 0; nt < 4; ++nt) {                                   \
                const int kg = (nt << 1) + (fr >> 3);                          \
                _Pragma("unroll")                                              \
                for (int r = 0; r < 4; ++r) {                                  \
                    const int q = mb * 16 + qr + r;                            \
                    tile[w * 2056 + q * 64 + ((kg ^ (q & 7)) << 3) +           \
                         (fr & 7)] =                                           \
                        (u16)(pk[mb][nt][r >> 1] >> ((r & 1) << 4));           \
                }                                                              \
            }                                                                  \
        _Pragma("unroll")                                                      \
        for (int mb = 0; mb < 2; ++mb) {                                       \
            const int q = mb * 16 + fr;                                        \
            _Pragma("unroll")                                                  \
            for (int kk = 0; kk < 2; ++kk) {                                   \
                short8 ap = *(const short8*)&tile[w * 2056 + q * 64 +          \
                    (((kk * 4 + hi4) ^ (q & 7)) << 3)];                        \
                _Pragma("unroll")                                              \
                for (int nt = 0; nt < 4; ++nt)                                 \
                    accP[mb][nt] = __builtin_amdgcn_mfma_f32_16x16x32_bf16(    \
                        ap, VB[nt][kk], accP[mb][nt], 0, 0, 0);                \
            }                                                                  \
        }                                                                      \
    }

    short8 v0[4][2], b0[4][2], v1[4][2], b1[4][2];
    LOADCH(v0, b0, kbase)
#pragma unroll
    for (int cc = 0; cc < 2; ++cc) {
        LOADCH(v1, b1, kbase + ((2 * cc + 1) << 6))
        COMPUTECH(v0, b0)
        if (cc < 1) { LOADCH(v0, b0, kbase + ((2 * cc + 2) << 6)) }
        COMPUTECH(v1, b1)
    }
#undef LOADCH
#undef COMPUTECH

    // epilogue: z reduce + partial writes
#pragma unroll
    for (int off = 1; off < 16; off <<= 1)
#pragma unroll
        for (int mb = 0; mb < 2; ++mb)
#pragma unroll
            for (int r = 0; r < 4; ++r)
                zacc[mb][r] += __shfl_xor(zacc[mb][r], off);
    if (fr == 0) {
#pragma unroll
        for (int mb = 0; mb < 2; ++mb)
#pragma unroll
            for (int r = 0; r < 4; ++r)
                zpart[((size_t)zsp * 8 + w) * NT + q0 + mb * 16 + qr + r] = zacc[mb][r];
    }
    float* pP = partsP + (size_t)zsp * NT * EMBD;
#pragma unroll
    for (int mb = 0; mb < 2; ++mb)
#pragma unroll
        for (int nt = 0; nt < 4; ++nt)
#pragma unroll
            for (int r = 0; r < 4; ++r)
                pP[(size_t)(q0 + mb * 16 + qr + r) * EMBD +
                   (w << 6) + (nt << 4) + fr] = accP[mb][nt][r];
}

// ==== bias_v: angles -> sincos -> MFMA head-proj -> bias@V (split-K=8) ======
// R10 structure (wave-private angles, double-buffered tile, 5 barriers) with
// phase-B sincos via HARMONIC RECURRENCE: freqs per lane are an arithmetic
// progression (step dphi = ((1/31)/0.1)*ang), so sin/cos for j=1..7 follow
// from j=0 by a fixed rotation (4 FMA/step) instead of per-j range-reduce +
// 2 trans. j=0 values remain bit-identical to R10 (same op chain); j>=1
// drift <= ~5e-4 — same order as the per-j f32 range-reduction error, and
// absorbed by the immediate bf16 quantization. First numerics-touching
// change of the session (R10 post-mortem: barriers/bank-conflicts/loads all
// eliminated, kernel still 62us -> trans issue is the remaining cost).
__global__ __launch_bounds__(512, 4) void bias_v(
    const u16* __restrict__ Vt, const float* __restrict__ vec,
    const float* __restrict__ Wb, const float* __restrict__ bb,
    float* __restrict__ partsB)
{
    __shared__ float flds[32];
    __shared__ float vql[96];
    __shared__ float angw[8 * 260];       // per-wave 256 angles (+4 pad)
    __shared__ u16 tile[2][8 * 2056];     // double-buffered bias tile

    const int bid = blockIdx.x;
    const int zsp = bid & 7;
    const int qt  = bid >> 3;
    const int q0 = qt << 5;
    const int kbase = zsp << 8;

    const int t = threadIdx.x;
    const int w = t >> 6;              // wave = head
    const int lane = t & 63;
    const int fr = lane & 15;
    const int hi4 = lane >> 4;
    const int kd = hi4 << 3;
    const int qr = hi4 << 2;

    if (t < 32) flds[t] = __fdiv_rn(__fdiv_rn((float)t, 31.0f), 0.1f);
    else if (t < 128) vql[t - 32] = vec[q0 * 3 + (t - 32)];

    // frequency step (bit-identical to flds[1]): (1/31)/0.1
    const float fld = __fdiv_rn(__fdiv_rn(1.0f, 31.0f), 0.1f);

    short8 BS, BC;
#pragma unroll
    for (int j = 0; j < 8; ++j) {
        float ws = (fr < 8) ? Wb[(kd + j) * 8 + fr] : 0.0f;
        float wc = (fr < 8) ? Wb[(32 + kd + j) * 8 + fr] : 0.0f;
        BS[j] = (short)f2bf(ws);
        BC[j] = (short)f2bf(wc);
    }
    const float bbv = (fr < 8) ? bb[fr] : 0.0f;

    v4f accB[2][4] = {};

    __syncthreads();   // prologue: flds/vql visible to all waves

    for (int c = 0; c < 4; ++c) {
        const int kc = kbase + (c << 6);
        u16* tp = tile[c & 1];
        // ---- phase A (wave-private): 4 angles/lane, frozen numerics
#pragma unroll
        for (int jj = 0; jj < 4; ++jj) {
            const int idx = lane + (jj << 6);       // 0..255, lane-contiguous
            const int gi = idx >> 4;
            const int g = w + (gi << 3);
            const int q = g >> 2;                   // 0..31
            const int kl = ((g & 3) << 4) + (idx & 15);
            const float a0 = vql[q * 3], a1 = vql[q * 3 + 1], a2 = vql[q * 3 + 2];
            const float* vk = vec + (size_t)(kc + kl) * 3;
            float c0 = vk[0], c1 = vk[1], c2 = vk[2];
            float dot = __fadd_rn(__fadd_rn(__fmul_rn(a0, c0), __fmul_rn(a1, c1)),
                                  __fmul_rn(a2, c2));
            float dotc = fminf(fmaxf(dot, 0.0f), 1.0f);
            angw[w * 260 + idx] = __fdiv_rn(acosf(dotc), 0.001f);
        }
        // (no barrier: wave w reads only angw[w*260..] in phase B)
        // ---- phase B: sincos via base + rotation recurrence -> bias tile
#pragma unroll
        for (int gi = 0; gi < 16; ++gi) {
            const int g = w + (gi << 3);
            const int q = g >> 2;
            const int ksub = (g & 3) << 4;
            const float av = angw[w * 260 + (gi << 4) + fr];
            float sv[8], cv[8];
            {
                // j=0: identical op chain to the direct path
                float ph0 = __fmul_rn(flds[kd], av);
                float rv0 = ph0 * 0.15915494309189535f;
                float rf0 = rv0 - floorf(rv0);
                float s = __builtin_amdgcn_sinf(rf0);
                float cc0 = __builtin_amdgcn_cosf(rf0);
                sv[0] = s; cv[0] = cc0;
                // rotation step: angle = fld*av (reduced once)
                float phd = __fmul_rn(fld, av);
                float rvd = phd * 0.15915494309189535f;
                float rfd = rvd - floorf(rvd);
                float sd = __builtin_amdgcn_sinf(rfd);
                float cd = __builtin_amdgcn_cosf(rfd);
                float cC = cc0;
#pragma unroll
                for (int j = 1; j < 8; ++j) {
                    float s2 = s * cd + cC * sd;
                    float c2 = cC * cd - s * sd;
                    s = s2; cC = c2;
                    sv[j] = s; cv[j] = cC;
                }
            }
            union { uint4 u; short8 v; } As, Ac;
            As.u.x = cvtpk(sv[0], sv[1]); As.u.y = cvtpk(sv[2], sv[3]);
            As.u.z = cvtpk(sv[4], sv[5]); As.u.w = cvtpk(sv[6], sv[7]);
            Ac.u.x = cvtpk(cv[0], cv[1]); Ac.u.y = cvtpk(cv[2], cv[3]);
            Ac.u.z = cvtpk(cv[4], cv[5]); Ac.u.w = cvtpk(cv[6], cv[7]);
            v4f cb = {};
            cb = __builtin_amdgcn_mfma_f32_16x16x32_bf16(As.v, BS, cb, 0, 0, 0);
            cb = __builtin_amdgcn_mfma_f32_16x16x32_bf16(Ac.v, BC, cb, 0, 0, 0);
            if (fr < 8) {
                const int kg = (ksub + qr) >> 3;
                uint2 wv;
                wv.x = cvtpk(cb[0] + bbv, cb[1] + bbv);
                wv.y = cvtpk(cb[2] + bbv, cb[3] + bbv);
                *(uint2*)&tp[fr * 2056 + q * 64 + ((kg ^ (q & 7)) << 3) + (qr & 7)] = wv;
            }
        }
        __syncthreads();   // the one real cross-wave handoff (B -> C)
        // ---- phase C: accB += bias@V (accum order verbatim)
#pragma unroll
        for (int kk = 0; kk < 2; ++kk) {
            const int q0l = 0 * 16 + fr, q1l = 1 * 16 + fr;
            short8 ab0 = *(const short8*)&tp[w * 2056 + q0l * 64 +
                (((kk * 4 + hi4) ^ (q0l & 7)) << 3)];
            short8 ab1 = *(const short8*)&tp[w * 2056 + q1l * 64 +
                (((kk * 4 + hi4) ^ (q1l & 7)) << 3)];
#pragma unroll
            for (int nt = 0; nt < 4; ++nt) {
                short8 vbx = *(const short8*)(Vt +
                    (size_t)(w * 64 + nt * 16 + fr) * NT + kc + kk * 32 + kd);
                accB[0][nt] = __builtin_amdgcn_mfma_f32_16x16x32_bf16(ab0, vbx, accB[0][nt], 0, 0, 0);
                accB[1][nt] = __builtin_amdgcn_mfma_f32_16x16x32_bf16(ab1, vbx, accB[1][nt], 0, 0, 0);
            }
        }
        // C(c) vs B(c+2) reuse of tile[c&1] is ordered by barrier(c+1).
    }
    float* pB = partsB + (size_t)zsp * NT * EMBD;
#pragma unroll
    for (int mb = 0; mb < 2; ++mb)
#pragma unroll
        for (int nt = 0; nt < 4; ++nt)
#pragma unroll
            for (int r = 0; r < 4; ++r)
                pB[(size_t)(q0 + mb * 16 + qr + r) * EMBD +
                   (w << 6) + (nt << 4) + fr] = accB[mb][nt][r];
}

// ------- reduce 8 partials: y = sumP/sumZ + sumB -> bf16 hi/lo --------------
__global__ __launch_bounds__(256) void reduce_y2(const float* __restrict__ partsP,
    const float* __restrict__ partsB, const float* __restrict__ zpart,
    u16* __restrict__ yh, u16* __restrict__ yl)
{
    const int MN = NT * EMBD;
    int i = (blockIdx.x * 256 + threadIdx.x) << 2;
    const int q = i >> 9;
    const int h = (i & 511) >> 6;
    float zs = 0.0f;
#pragma unroll
    for (int z = 0; z < KSPLIT; ++z) zs += zpart[((size_t)z * 8 + h) * NT + q];
    float4 aP = *(const float4*)(partsP + i);
    float4 aB = *(const float4*)(partsB + i);
#pragma unroll
    for (int z = 1; z < KSPLIT; ++z) {
        float4 p = *(const float4*)(partsP + (size_t)z * MN + i);
        float4 b = *(const float4*)(partsB + (size_t)z * MN + i);
        aP.x += p.x; aP.y += p.y; aP.z += p.z; aP.w += p.w;
        aB.x += b.x; aB.y += b.y; aB.z += b.z; aB.w += b.w;
    }
    const float iz = 1.0f / zs;
    float f[4] = {aP.x * iz + aB.x, aP.y * iz + aB.y,
                  aP.z * iz + aB.z, aP.w * iz + aB.w};
    unsigned int hi[4], lo[4];
#pragma unroll
    for (int j = 0; j < 4; ++j) {
        hi[j] = f2bf(f[j]);
        lo[j] = f2bf(f[j] - bf2f(hi[j]));
    }
    uint2 wh; wh.x = hi[0] | (hi[1] << 16); wh.y = hi[2] | (hi[3] << 16);
    uint2 wl; wl.x = lo[0] | (lo[1] << 16); wl.y = lo[2] | (lo[3] << 16);
    *(uint2*)(yh + i) = wh;
    *(uint2*)(yl + i) = wl;
}

// ------- out = y @ Wout + bout via split-precision bf16 MFMA ----------------
__global__ __launch_bounds__(256) void gemm_out_mfma(const u16* __restrict__ yh,
    const u16* __restrict__ yl, const u16* __restrict__ wh,
    const u16* __restrict__ wl, const float* __restrict__ bias,
    float* __restrict__ out)
{
    const int n0 = blockIdx.x << 6, m0 = blockIdx.y << 6;
    const int w = threadIdx.x >> 6, lane = threadIdx.x & 63;
    const int wm = w >> 1, wn = w & 1;
    const int fr = lane & 15, kd = (lane >> 4) << 3;

    const u16* ah0 = yh + (size_t)(m0 + wm * 32 + fr) * EMBD + kd;
    const u16* al0 = yl + (size_t)(m0 + wm * 32 + fr) * EMBD + kd;
    const u16* bh0 = wh + (size_t)(n0 + wn * 32 + fr) * EMBD + kd;
    const u16* bl0 = wl + (size_t)(n0 + wn * 32 + fr) * EMBD + kd;

    v4f acc[2][2] = {};
    for (int kc = 0; kc < EMBD; kc += 32) {
        short8 a_h[2], a_l[2], b_h[2], b_l[2];
#pragma unroll
        for (int im = 0; im < 2; ++im) {
            a_h[im] = *(const short8*)(ah0 + (size_t)im * 16 * EMBD + kc);
            a_l[im] = *(const short8*)(al0 + (size_t)im * 16 * EMBD + kc);
        }
#pragma unroll
        for (int in = 0; in < 2; ++in) {
            b_h[in] = *(const short8*)(bh0 + (size_t)in * 16 * EMBD + kc);
            b_l[in] = *(const short8*)(bl0 + (size_t)in * 16 * EMBD + kc);
        }
#pragma unroll
        for (int im = 0; im < 2; ++im)
#pragma unroll
            for (int in = 0; in < 2; ++in) {
                acc[im][in] = __builtin_amdgcn_mfma_f32_16x16x32_bf16(a_h[im], b_h[in], acc[im][in], 0, 0, 0);
                acc[im][in] = __builtin_amdgcn_mfma_f32_16x16x32_bf16(a_h[im], b_l[in], acc[im][in], 0, 0, 0);
                acc[im][in] = __builtin_amdgcn_mfma_f32_16x16x32_bf16(a_l[im], b_h[in], acc[im][in], 0, 0, 0);
            }
    }
    const int qr = (lane >> 4) << 2;
#pragma unroll
    for (int im = 0; im < 2; ++im)
#pragma unroll
        for (int in = 0; in < 2; ++in) {
            int n = n0 + wn * 32 + in * 16 + fr;
            float bv = bias[n];
#pragma unroll
            for (int r = 0; r < 4; ++r) {
                int m = m0 + wm * 32 + im * 16 + qr + r;
                out[(size_t)m * EMBD + n] = acc[im][in][r] + bv;
            }
        }
}

extern "C" void kernel_launch(void* const* d_in, const int* in_sizes, int n_in,
                              void* d_out, int out_size, void* d_ws, size_t ws_size,
                              hipStream_t stream)
{
    const float* x    = (const float*)d_in[0];
    const float* vec  = (const float*)d_in[1];
    const float* Wqkv = (const float*)d_in[2];
    const float* bqkv = (const float*)d_in[3];
    const float* Wb   = (const float*)d_in[4];
    const float* bb   = (const float*)d_in[5];
    const float* Wout = (const float*)d_in[6];
    const float* bout = (const float*)d_in[7];
    float* out = (float*)d_out;

    char* ws = (char*)d_ws;
    u16*   qkvb   = (u16*)(ws);                     //  6,291,456
    u16*   Vt     = (u16*)(ws + 6291456);           //  2,097,152
    float* zpart  = (float*)(ws + 8388608);         //    524,288 (8*8*2048*4)
    float* partsP = (float*)(ws + 8912896);         // 33,554,432
    float* partsB = (float*)(ws + 42467328);        // 33,554,432
    u16*   yh     = (u16*)(ws + 76021760);          //  2,097,152
    u16*   yl     = (u16*)(ws + 78118912);          //  2,097,152
    u16*   xh     = (u16*)(ws + 80216064);          //  2,097,152
    u16*   xl     = (u16*)(ws + 82313216);          //  2,097,152
    u16*   wth    = (u16*)(ws + 84410368);          //  1,572,864
    u16*   wtl    = (u16*)(ws + 85983232);          //  1,572,864
    u16*   woth   = (u16*)(ws + 87556096);          //    524,288
    u16*   wotl   = (u16*)(ws + 88080384);          //    524,288
    // total: 88,604,672 B

    prep<<<1280, 256, 0, stream>>>(x, xh, xl, Wqkv, wth, wtl, Wout, woth, wotl);
    gemm_qkv_mfma<<<dim3(24, 32), 256, 0, stream>>>(xh, xl, wth, wtl, bqkv, qkvb);
    transpose_v<<<dim3(32, 8), 256, 0, stream>>>(qkvb, Vt);
    bias_v<<<64 * KSPLIT, 512, 0, stream>>>(Vt, vec, Wb, bb, partsB);
    attn_pv<<<64 * KSPLIT, 512, 0, stream>>>(qkvb, Vt, zpart, partsP);
    reduce_y2<<<1024, 256, 0, stream>>>(partsP, partsB, zpart, yh, yl);
    gemm_out_mfma<<<dim3(8, 32), 256, 0, stream>>>(yh, yl, woth, wotl, bout, out);
}